// Round 15
// baseline (98.744 us; speedup 1.0000x reference)
//
#include <hip/hip_runtime.h>
#include <cstdint>
#include <cstddef>

typedef unsigned short u16;
typedef unsigned char u8;
typedef __bf16 bf16x8 __attribute__((ext_vector_type(8)));
typedef float f32x4 __attribute__((ext_vector_type(4)));
typedef float f32x2 __attribute__((ext_vector_type(2)));
typedef u16 u16x4 __attribute__((ext_vector_type(4)));
typedef u16 u16x8 __attribute__((ext_vector_type(8)));

#define B_ 16384
#define D_ 64
#define MAXC_ 8
#define NCON_ 2000
#define NCONP_ 2048
#define TDIM_ 1024
#define HID_ 256

#define VMW(n) asm volatile("s_waitcnt vmcnt(" #n ")" ::: "memory")
#define BAR() __builtin_amdgcn_s_barrier()

__device__ inline u16 f2b(float f){
  unsigned u = __float_as_uint(f);
  u += 0x7fffu + ((u >> 16) & 1u);
  return (u16)(u >> 16);
}
__device__ inline float b2f(u16 u){ return __uint_as_float(((unsigned)u) << 16); }

__device__ inline unsigned pk2fp8(float a, float b){
  return (unsigned)__builtin_amdgcn_cvt_pk_fp8_f32(a, b, 0, false);
}
template<bool HI>
__device__ inline f32x2 unpk_fp8(unsigned v){
  return __builtin_amdgcn_cvt_pk_f32_fp8(v, HI);
}

__device__ inline void gload16(const void* g, void* l){
  __builtin_amdgcn_global_load_lds((const __attribute__((address_space(1))) unsigned*)g,
                                   (__attribute__((address_space(3))) unsigned*)l, 16, 0, 0);
}

__device__ inline float wsum(float v){
  #pragma unroll
  for (int o = 32; o; o >>= 1) v += __shfl_xor(v, o);
  return v;
}
__device__ inline float sigf(float x){ return 1.f / (1.f + __expf(-x)); }

// =================== k_prep (exact R8) ======================================
__global__ __launch_bounds__(256) void k_prep(
    const float* __restrict__ ex, const int* __restrict__ pid,
    const float* __restrict__ con,
    const float* __restrict__ W1, const float* __restrict__ W2,
    const float* __restrict__ Wx, const float* __restrict__ Wh,
    const float* __restrict__ bx, const float* __restrict__ bh,
    u16* __restrict__ qb, float* __restrict__ qn,
    u16* __restrict__ cb, u8* __restrict__ cb8, float* __restrict__ cn,
    u16* __restrict__ W1T, u16* __restrict__ W2T, u16* __restrict__ WxhT,
    float* __restrict__ bxh)
{
  const int bid = blockIdx.x, tid = threadIdx.x;
  const int lane = tid & 63;
  if (bid < 4096){                                  // ---- q gather ----
    const int b = bid * 4 + (tid >> 6);
    const float* src = ex + (size_t)pid[b] * TDIM_;
    u16* dst = qb + (size_t)b * TDIM_;
    float ss = 0.f;
    #pragma unroll
    for (int c = 0; c < 4; ++c){
      float4 v = *(const float4*)(src + c * 256 + lane * 4);
      ss += v.x*v.x + v.y*v.y + v.z*v.z + v.w*v.w;
      u16x4 o = { f2b(v.x), f2b(v.y), f2b(v.z), f2b(v.w) };
      *(u16x4*)(dst + c * 256 + lane * 4) = o;
    }
    ss = wsum(ss);
    if (lane == 0) qn[b] = sqrtf(ss);
  } else if (bid < 4608){                           // ---- concepts ----
    const int r = (bid - 4096) * 4 + (tid >> 6);
    u16* dst = cb + (size_t)r * TDIM_;
    u8*  dst8 = cb8 + (size_t)r * TDIM_;
    if (r < NCON_){
      const float* src = con + (size_t)r * TDIM_;
      float ss = 0.f;
      #pragma unroll
      for (int c = 0; c < 4; ++c){
        float4 v = *(const float4*)(src + c * 256 + lane * 4);
        ss += v.x*v.x + v.y*v.y + v.z*v.z + v.w*v.w;
        u16x4 o = { f2b(v.x), f2b(v.y), f2b(v.z), f2b(v.w) };
        *(u16x4*)(dst + c * 256 + lane * 4) = o;
        unsigned lo = pk2fp8(v.x * 32.f, v.y * 32.f);
        unsigned hi = pk2fp8(v.z * 32.f, v.w * 32.f);
        *(unsigned*)(dst8 + c * 256 + lane * 4) = (lo & 0xffffu) | (hi << 16);
      }
      ss = wsum(ss);
      if (lane == 0) cn[r] = sqrtf(ss);
    } else {
      u16x4 z = { 0, 0, 0, 0 };
      #pragma unroll
      for (int c = 0; c < 4; ++c){
        *(u16x4*)(dst + c * 256 + lane * 4) = z;
        *(unsigned*)(dst8 + c * 256 + lane * 4) = 0u;
      }
    }
  } else {                                          // ---- weights ----
    int gid = (bid - 4608) * 256 + tid;
    if (gid < 262144){                       // W1T: n*1024 + k
      int n = gid >> 10, k = gid & 1023;
      W1T[gid] = f2b(W1[(size_t)k * 256 + n]);
    } else if (gid < 278528){                // W2T: n*256 + k
      int t = gid - 262144;
      int n = t >> 8, k = t & 255;
      W2T[t] = f2b(W2[(size_t)k * 64 + n]);
    } else if (gid < 360448){                // WxhT: c*320 + k, gate-interleaved
      int t = gid - 278528;
      int c = t / 320, k = t % 320;
      int g = (c >> 4) & 3;
      int d = (c >> 6) * 16 + (c & 15);
      float v = 0.f;
      if (k < 256){
        if (g == 0)      v = Wx[(size_t)k * 192 + d];
        else if (g == 1) v = Wx[(size_t)k * 192 + 64 + d];
        else if (g == 2) v = Wx[(size_t)k * 192 + 128 + d];
      } else {
        int kh = k - 256;
        if (g == 0)      v = Wh[(size_t)kh * 192 + d];
        else if (g == 1) v = Wh[(size_t)kh * 192 + 64 + d];
        else if (g == 3) v = Wh[(size_t)kh * 192 + 128 + d];
      }
      WxhT[t] = f2b(v);
    } else if (gid < 360704){                // bxh
      int c = gid - 360448;
      int g = (c >> 4) & 3;
      int d = (c >> 6) * 16 + (c & 15);
      float v;
      if (g == 0)      v = bx[d] + bh[d];
      else if (g == 1) v = bx[64 + d] + bh[64 + d];
      else if (g == 2) v = bx[128 + d];
      else             v = bh[128 + d];
      bxh[c] = v;
    }
  }
}

// =================== k_mlp (exact R8): red = relu(A@W1+b1)@W2+b2 ============
__global__ __launch_bounds__(512) void k_mlp(
    const u16* __restrict__ qb, const u16* __restrict__ cb,
    const u16* __restrict__ W1T, const float* __restrict__ b1,
    const u16* __restrict__ W2T, const float* __restrict__ b2,
    float* __restrict__ redq, float* __restrict__ redc)
{
  __shared__ u16 As[32 * 64];      // 4 KB
  __shared__ u16 Bs[256 * 64];     // 32 KB
  __shared__ u16 Hs[32 * 256];     // 16 KB
  const int tid = threadIdx.x;
  const int lane = tid & 63;
  const int w = tid >> 6;
  const int lr = lane & 15, lq = lane >> 4;
  const bool qside = blockIdx.x < 512;
  const u16* Abase = qside ? qb : cb;
  float* Obase = qside ? redq : redc;
  const int m0 = (qside ? (int)blockIdx.x : ((int)blockIdx.x - 512)) << 5;
  const int rf = w & 1, ch = w >> 1;
  const int arow = tid >> 3, asub = tid & 7;

  f32x4 acc[4] = {};
  for (int kt = 0; kt < 16; ++kt){
    if (tid < 256)
      gload16(Abase + (size_t)(m0 + arow) * 1024 + kt * 64 + ((asub ^ (arow & 7)) << 3),
              &As[tid * 8]);
    #pragma unroll
    for (int i = 0; i < 4; ++i){
      int cc = i * 512 + tid;
      int r2 = cc >> 3, s2 = cc & 7;
      gload16(W1T + (size_t)r2 * 1024 + kt * 64 + ((s2 ^ (r2 & 7)) << 3), &Bs[cc * 8]);
    }
    VMW(0);
    BAR();
    #pragma unroll
    for (int ks = 0; ks < 2; ++ks){
      const int kb = ks * 64 + lq * 16;
      const int ra = rf * 16 + lr;
      bf16x8 af = *(const bf16x8*)((const char*)As + ra * 128 + (kb ^ ((ra & 7) << 4)));
      #pragma unroll
      for (int fc = 0; fc < 4; ++fc){
        int rb = ch * 64 + fc * 16 + lr;
        bf16x8 bf = *(const bf16x8*)((const char*)Bs + rb * 128 + (kb ^ ((rb & 7) << 4)));
        acc[fc] = __builtin_amdgcn_mfma_f32_16x16x32_bf16(af, bf, acc[fc], 0, 0, 0);
      }
    }
    BAR();
  }
  #pragma unroll
  for (int fc = 0; fc < 4; ++fc){
    int col = ch * 64 + fc * 16 + lr;
    float bv = b1[col];
    #pragma unroll
    for (int j = 0; j < 4; ++j){
      int rr = rf * 16 + lq * 4 + j;
      float v = fmaxf(acc[fc][j] + bv, 0.f);
      *(u16*)((char*)Hs + rr * 512 + ((col * 2) ^ ((rr & 7) << 4))) = f2b(v);
    }
  }
  __syncthreads();
  const int rf2 = w & 1, cp = w >> 1;
  f32x4 acc2 = {};
  #pragma unroll
  for (int ks2 = 0; ks2 < 8; ++ks2){
    int rr = rf2 * 16 + lr;
    int kb2 = ks2 * 64 + lq * 16;
    bf16x8 af2 = *(const bf16x8*)((const char*)Hs + rr * 512 + (kb2 ^ ((rr & 7) << 4)));
    bf16x8 w2 = *(const bf16x8*)(W2T + (size_t)(cp * 16 + lr) * 256 + ks2 * 32 + lq * 8);
    acc2 = __builtin_amdgcn_mfma_f32_16x16x32_bf16(af2, w2, acc2, 0, 0, 0);
  }
  {
    int col = cp * 16 + lr;
    float bv = b2[col];
    #pragma unroll
    for (int j = 0; j < 4; ++j){
      int rr = m0 + rf2 * 16 + lq * 4 + j;
      Obase[(size_t)rr * 64 + col] = acc2[j] + bv;
    }
  }
}

// =================== k_mixgru: 1024 blocks x 16 rows, no staging ============
// Mix: 2 rows/wave (R8-style). GRU GEMM: no LDS staging; B-fragments read
// directly from L2-resident WxhT. K-split: waves 0-3 K[0,192), waves 4-7
// K[192,320) -> partials via LDS. LDS 28 KB -> occupancy wave-slot-limited.
__global__ __launch_bounds__(512, 4) void k_mixgru(
    const u16* __restrict__ qb, const u8* __restrict__ cb8,
    const float* __restrict__ qn, const float* __restrict__ cn,
    const int* __restrict__ rci, const int* __restrict__ filt,
    const float* __restrict__ redq, const float* __restrict__ redc,
    const float* __restrict__ h, const float* __restrict__ emb,
    const float* __restrict__ op, const float* __restrict__ Wp,
    const float* __restrict__ bp, const u16* __restrict__ WxhT,
    const float* __restrict__ bxh, float* __restrict__ prob_out,
    float* __restrict__ outh)
{
  __shared__ u16 XH[16 * 320];          // 10 KB, row stride 640 B, swizzled
  __shared__ float PS[4][16][68];       // 17 KB partials (padded: no 4-way bank hit)
  const int tid = threadIdx.x;
  const int lane = tid & 63;
  const int w = tid >> 6;
  const int m0 = blockIdx.x << 4;

  // ---------------- mix phase: 2 rows per wave ----------------
  for (int i = 0; i < 2; ++i){
    const int r = w * 2 + i;
    const int b = m0 + r;
    const u16* qrow = qb + (size_t)b * TDIM_ + lane * 16;
    u16x8 qa = *(const u16x8*)qrow;
    u16x8 qc = *(const u16x8*)(qrow + 8);
    float qf[16];
    #pragma unroll
    for (int k = 0; k < 8; ++k){ qf[k] = b2f(qa[k]); qf[8 + k] = b2f(qc[k]); }
    int idxm[MAXC_];
    #pragma unroll
    for (int m = 0; m < MAXC_; ++m) idxm[m] = rci[b * MAXC_ + m];
    float dots[MAXC_];
    #pragma unroll
    for (int m = 0; m < MAXC_; ++m){
      uint4 cw = *(const uint4*)(cb8 + (size_t)idxm[m] * TDIM_ + lane * 16);
      float s = 0.f; f32x2 p;
      p = unpk_fp8<false>(cw.x); s += qf[0]*p[0]  + qf[1]*p[1];
      p = unpk_fp8<true >(cw.x); s += qf[2]*p[0]  + qf[3]*p[1];
      p = unpk_fp8<false>(cw.y); s += qf[4]*p[0]  + qf[5]*p[1];
      p = unpk_fp8<true >(cw.y); s += qf[6]*p[0]  + qf[7]*p[1];
      p = unpk_fp8<false>(cw.z); s += qf[8]*p[0]  + qf[9]*p[1];
      p = unpk_fp8<true >(cw.z); s += qf[10]*p[0] + qf[11]*p[1];
      p = unpk_fp8<false>(cw.w); s += qf[12]*p[0] + qf[13]*p[1];
      p = unpk_fp8<true >(cw.w); s += qf[14]*p[0] + qf[15]*p[1];
      dots[m] = s;
    }
    #pragma unroll
    for (int o = 32; o; o >>= 1){
      #pragma unroll
      for (int m = 0; m < MAXC_; ++m) dots[m] += __shfl_xor(dots[m], o);
    }
    const float qnb = qn[b];
    float sv[MAXC_]; float mx = -3.0e38f;
    #pragma unroll
    for (int m = 0; m < MAXC_; ++m){
      float dnm = fmaxf(qnb * cn[idxm[m]], 1e-8f);
      float s = (filt[b * MAXC_ + m] == 0) ? -1e9f : dots[m] * (1.f / 32.f) / dnm;
      sv[m] = s; mx = fmaxf(mx, s);
    }
    float se = 0.f;
    #pragma unroll
    for (int m = 0; m < MAXC_; ++m){ sv[m] = __expf(sv[m] - mx); se += sv[m]; }
    const float inv = 1.f / se;
    float rep = 0.f;
    #pragma unroll
    for (int m = 0; m < MAXC_; ++m) rep += sv[m] * redc[(size_t)idxm[m] * D_ + lane];
    rep *= inv;
    const float v0 = redq[(size_t)b * D_ + lane];
    const float hv = h[(size_t)b * D_ + lane];
    const float e0 = emb[(size_t)b * 128 + lane];
    const float e1 = emb[(size_t)b * 128 + 64 + lane];
    float p = hv * Wp[lane] + v0 * Wp[64 + lane] + rep * Wp[128 + lane]
            + e0 * Wp[192 + lane] + e1 * Wp[256 + lane];
    p = wsum(p);
    if (lane == 0) prob_out[b] = p + bp[0];
    const float o = op[b], om = 1.f - o;
    auto xst = [&](int col, float v){
      *(u16*)((char*)XH + r * 640 + ((col * 2) ^ ((r & 7) << 4))) = f2b(v);
    };
    xst(lane,        v0 * o  + e0 * om);
    xst(64 + lane,   rep * o + e1 * om);
    xst(128 + lane,  v0 * om + e0 * o);
    xst(192 + lane,  rep * om + e1 * o);
    xst(256 + lane,  hv);
  }
  __syncthreads();

  // ---------------- GRU GEMM: [16,320]@[320,256], K-split, no staging ------
  const int lr = lane & 15, lq = lane >> 4;
  const int cc = w & 3, kh = w >> 2;
  f32x4 acc[4] = {};
  const int kt0 = kh ? 3 : 0, kt1 = kh ? 5 : 3;
  for (int kt = kt0; kt < kt1; ++kt){
    #pragma unroll
    for (int ks = 0; ks < 2; ++ks){
      const int kb = ks * 64 + lq * 16;
      bf16x8 af = *(const bf16x8*)((const char*)XH + lr * 640 +
                                   ((kt * 128 + kb) ^ ((lr & 7) << 4)));
      #pragma unroll
      for (int fc = 0; fc < 4; ++fc){
        int rb = cc * 64 + fc * 16 + lr;
        bf16x8 bf = *(const bf16x8*)(WxhT + (size_t)rb * 320 + kt * 64 + ks * 32 + lq * 8);
        acc[fc] = __builtin_amdgcn_mfma_f32_16x16x32_bf16(af, bf, acc[fc], 0, 0, 0);
      }
    }
  }
  if (kh == 1){
    #pragma unroll
    for (int fc = 0; fc < 4; ++fc)
      #pragma unroll
      for (int j = 0; j < 4; ++j)
        PS[cc][lq * 4 + j][fc * 16 + lr] = acc[fc][j];
  }
  __syncthreads();
  if (kh == 0){
    const int d = cc * 16 + lr;
    float bg[4];
    #pragma unroll
    for (int g = 0; g < 4; ++g) bg[g] = bxh[cc * 64 + g * 16 + lr];
    #pragma unroll
    for (int j = 0; j < 4; ++j){
      const int row = lq * 4 + j;
      float a0 = acc[0][j] + PS[cc][row][lr];
      float a1 = acc[1][j] + PS[cc][row][16 + lr];
      float a2 = acc[2][j] + PS[cc][row][32 + lr];
      float a3 = acc[3][j] + PS[cc][row][48 + lr];
      float rv = sigf(a0 + bg[0]);
      float zv = sigf(a1 + bg[1]);
      float nv = tanhf(a2 + bg[2] + rv * (a3 + bg[3]));
      int rr = m0 + row;
      float hv = h[(size_t)rr * 64 + d];
      outh[(size_t)rr * 64 + d] = (1.f - zv) * nv + zv * hv;
    }
  }
}

extern "C" void kernel_launch(void* const* d_in, const int* in_sizes, int n_in,
                              void* d_out, int out_size, void* d_ws, size_t ws_size,
                              hipStream_t stream) {
  const int*   prob_ids = (const int*)  d_in[0];
  const int*   rci      = (const int*)  d_in[1];
  const int*   filt     = (const int*)  d_in[2];
  const float* h        = (const float*)d_in[3];
  const float* emb      = (const float*)d_in[4];
  const float* op       = (const float*)d_in[5];
  const float* ex       = (const float*)d_in[6];
  const float* con      = (const float*)d_in[7];
  const float* W1       = (const float*)d_in[8];
  const float* b1       = (const float*)d_in[9];
  const float* W2       = (const float*)d_in[10];
  const float* b2       = (const float*)d_in[11];
  const float* Wp       = (const float*)d_in[12];
  const float* bp       = (const float*)d_in[13];
  const float* Wx       = (const float*)d_in[14];
  const float* Wh       = (const float*)d_in[15];
  const float* bx       = (const float*)d_in[16];
  const float* bh       = (const float*)d_in[17];
  float* out = (float*)d_out;

  char* w = (char*)d_ws;
  size_t off = 0;
  auto alloc = [&](size_t bytes){ size_t o = off; off = (off + bytes + 255) & ~(size_t)255; return o; };
  u16*   qb   = (u16*)  (w + alloc((size_t)B_ * TDIM_ * 2));      // 32 MB
  u16*   cb   = (u16*)  (w + alloc((size_t)NCONP_ * TDIM_ * 2));  // 4 MB
  u8*    cb8  = (u8*)   (w + alloc((size_t)NCONP_ * TDIM_));      // 2 MB
  float* qn   = (float*)(w + alloc((size_t)B_ * 4));
  float* cn   = (float*)(w + alloc((size_t)NCONP_ * 4));
  float* redq = (float*)(w + alloc((size_t)B_ * D_ * 4));         // 4 MB
  float* redc = (float*)(w + alloc((size_t)NCONP_ * D_ * 4));
  u16*   W1T  = (u16*)  (w + alloc((size_t)HID_ * TDIM_ * 2));
  u16*   W2T  = (u16*)  (w + alloc((size_t)D_ * HID_ * 2));
  u16*   WxhT = (u16*)  (w + alloc((size_t)256 * 320 * 2));
  float* bxh  = (float*)(w + alloc((size_t)256 * 4));

  k_prep<<<6017, 256, 0, stream>>>(ex, prob_ids, con, W1, W2, Wx, Wh, bx, bh,
                                   qb, qn, cb, cb8, cn, W1T, W2T, WxhT, bxh);
  k_mlp<<<576, 512, 0, stream>>>(qb, cb, W1T, b1, W2T, b2, redq, redc);
  k_mixgru<<<1024, 512, 0, stream>>>(qb, cb8, qn, cn, rci, filt, redq, redc,
                                     h, emb, op, Wp, bp, WxhT, bxh, out, out + B_);
}

// Round 16
// 85.225 us; speedup vs baseline: 1.1586x; 1.1586x over previous
//
#include <hip/hip_runtime.h>
#include <cstdint>
#include <cstddef>

typedef unsigned short u16;
typedef unsigned char u8;
typedef long long i64;
typedef __bf16 bf16x8 __attribute__((ext_vector_type(8)));
typedef float f32x4 __attribute__((ext_vector_type(4)));
typedef u16 u16x4 __attribute__((ext_vector_type(4)));
typedef u16 u16x8 __attribute__((ext_vector_type(8)));

#define B_ 16384
#define D_ 64
#define MAXC_ 8
#define NCON_ 2000
#define NCONP_ 2048
#define TDIM_ 1024
#define HID_ 256

#define VMW(n) asm volatile("s_waitcnt vmcnt(" #n ")" ::: "memory")
#define BAR() __builtin_amdgcn_s_barrier()

__device__ inline u16 f2b(float f){
  unsigned u = __float_as_uint(f);
  u += 0x7fffu + ((u >> 16) & 1u);
  return (u16)(u >> 16);
}
__device__ inline float b2f(u16 u){ return __uint_as_float(((unsigned)u) << 16); }

__device__ inline unsigned pk2fp8(float a, float b){
  return (unsigned)__builtin_amdgcn_cvt_pk_fp8_f32(a, b, 0, false);
}

__device__ inline void gload16(const void* g, void* l){
  __builtin_amdgcn_global_load_lds((const __attribute__((address_space(1))) unsigned*)g,
                                   (__attribute__((address_space(3))) unsigned*)l, 16, 0, 0);
}

__device__ inline float wsum(float v){
  #pragma unroll
  for (int o = 32; o; o >>= 1) v += __shfl_xor(v, o);
  return v;
}
__device__ inline float sigf(float x){ return 1.f / (1.f + __expf(-x)); }

// =================== k_prep (R8 + qb8 fp8 output) ===========================
__global__ __launch_bounds__(256) void k_prep(
    const float* __restrict__ ex, const int* __restrict__ pid,
    const float* __restrict__ con,
    const float* __restrict__ W1, const float* __restrict__ W2,
    const float* __restrict__ Wx, const float* __restrict__ Wh,
    const float* __restrict__ bx, const float* __restrict__ bh,
    u16* __restrict__ qb, u8* __restrict__ qb8, float* __restrict__ qn,
    u16* __restrict__ cb, u8* __restrict__ cb8, float* __restrict__ cn,
    u16* __restrict__ W1T, u16* __restrict__ W2T, u16* __restrict__ WxhT,
    float* __restrict__ bxh)
{
  const int bid = blockIdx.x, tid = threadIdx.x;
  const int lane = tid & 63;
  if (bid < 4096){                                  // ---- q gather ----
    const int b = bid * 4 + (tid >> 6);
    const float* src = ex + (size_t)pid[b] * TDIM_;
    u16* dst = qb + (size_t)b * TDIM_;
    u8*  dst8 = qb8 + (size_t)b * TDIM_;
    float ss = 0.f;
    #pragma unroll
    for (int c = 0; c < 4; ++c){
      float4 v = *(const float4*)(src + c * 256 + lane * 4);
      ss += v.x*v.x + v.y*v.y + v.z*v.z + v.w*v.w;
      u16x4 o = { f2b(v.x), f2b(v.y), f2b(v.z), f2b(v.w) };
      *(u16x4*)(dst + c * 256 + lane * 4) = o;
      unsigned lo = pk2fp8(v.x * 32.f, v.y * 32.f);
      unsigned hi = pk2fp8(v.z * 32.f, v.w * 32.f);
      *(unsigned*)(dst8 + c * 256 + lane * 4) = (lo & 0xffffu) | (hi << 16);
    }
    ss = wsum(ss);
    if (lane == 0) qn[b] = sqrtf(ss);
  } else if (bid < 4608){                           // ---- concepts ----
    const int r = (bid - 4096) * 4 + (tid >> 6);
    u16* dst = cb + (size_t)r * TDIM_;
    u8*  dst8 = cb8 + (size_t)r * TDIM_;
    if (r < NCON_){
      const float* src = con + (size_t)r * TDIM_;
      float ss = 0.f;
      #pragma unroll
      for (int c = 0; c < 4; ++c){
        float4 v = *(const float4*)(src + c * 256 + lane * 4);
        ss += v.x*v.x + v.y*v.y + v.z*v.z + v.w*v.w;
        u16x4 o = { f2b(v.x), f2b(v.y), f2b(v.z), f2b(v.w) };
        *(u16x4*)(dst + c * 256 + lane * 4) = o;
        unsigned lo = pk2fp8(v.x * 32.f, v.y * 32.f);
        unsigned hi = pk2fp8(v.z * 32.f, v.w * 32.f);
        *(unsigned*)(dst8 + c * 256 + lane * 4) = (lo & 0xffffu) | (hi << 16);
      }
      ss = wsum(ss);
      if (lane == 0) cn[r] = sqrtf(ss);
    } else {
      u16x4 z = { 0, 0, 0, 0 };
      #pragma unroll
      for (int c = 0; c < 4; ++c){
        *(u16x4*)(dst + c * 256 + lane * 4) = z;
        *(unsigned*)(dst8 + c * 256 + lane * 4) = 0u;
      }
    }
  } else {                                          // ---- weights ----
    int gid = (bid - 4608) * 256 + tid;
    if (gid < 262144){                       // W1T: n*1024 + k
      int n = gid >> 10, k = gid & 1023;
      W1T[gid] = f2b(W1[(size_t)k * 256 + n]);
    } else if (gid < 278528){                // W2T: n*256 + k
      int t = gid - 262144;
      int n = t >> 8, k = t & 255;
      W2T[t] = f2b(W2[(size_t)k * 64 + n]);
    } else if (gid < 360448){                // WxhT: c*320 + k, gate-interleaved
      int t = gid - 278528;
      int c = t / 320, k = t % 320;
      int g = (c >> 4) & 3;
      int d = (c >> 6) * 16 + (c & 15);
      float v = 0.f;
      if (k < 256){
        if (g == 0)      v = Wx[(size_t)k * 192 + d];
        else if (g == 1) v = Wx[(size_t)k * 192 + 64 + d];
        else if (g == 2) v = Wx[(size_t)k * 192 + 128 + d];
      } else {
        int kh = k - 256;
        if (g == 0)      v = Wh[(size_t)kh * 192 + d];
        else if (g == 1) v = Wh[(size_t)kh * 192 + 64 + d];
        else if (g == 3) v = Wh[(size_t)kh * 192 + 128 + d];
      }
      WxhT[t] = f2b(v);
    } else if (gid < 360704){                // bxh
      int c = gid - 360448;
      int g = (c >> 4) & 3;
      int d = (c >> 6) * 16 + (c & 15);
      float v;
      if (g == 0)      v = bx[d] + bh[d];
      else if (g == 1) v = bx[64 + d] + bh[64 + d];
      else if (g == 2) v = bx[128 + d];
      else             v = bh[128 + d];
      bxh[c] = v;
    }
  }
}

// =================== k_mlp (exact R8): red = relu(A@W1+b1)@W2+b2 ============
__global__ __launch_bounds__(512) void k_mlp(
    const u16* __restrict__ qb, const u16* __restrict__ cb,
    const u16* __restrict__ W1T, const float* __restrict__ b1,
    const u16* __restrict__ W2T, const float* __restrict__ b2,
    float* __restrict__ redq, float* __restrict__ redc)
{
  __shared__ u16 As[32 * 64];      // 4 KB
  __shared__ u16 Bs[256 * 64];     // 32 KB
  __shared__ u16 Hs[32 * 256];     // 16 KB
  const int tid = threadIdx.x;
  const int lane = tid & 63;
  const int w = tid >> 6;
  const int lr = lane & 15, lq = lane >> 4;
  const bool qside = blockIdx.x < 512;
  const u16* Abase = qside ? qb : cb;
  float* Obase = qside ? redq : redc;
  const int m0 = (qside ? (int)blockIdx.x : ((int)blockIdx.x - 512)) << 5;
  const int rf = w & 1, ch = w >> 1;
  const int arow = tid >> 3, asub = tid & 7;

  f32x4 acc[4] = {};
  for (int kt = 0; kt < 16; ++kt){
    if (tid < 256)
      gload16(Abase + (size_t)(m0 + arow) * 1024 + kt * 64 + ((asub ^ (arow & 7)) << 3),
              &As[tid * 8]);
    #pragma unroll
    for (int i = 0; i < 4; ++i){
      int cc = i * 512 + tid;
      int r2 = cc >> 3, s2 = cc & 7;
      gload16(W1T + (size_t)r2 * 1024 + kt * 64 + ((s2 ^ (r2 & 7)) << 3), &Bs[cc * 8]);
    }
    VMW(0);
    BAR();
    #pragma unroll
    for (int ks = 0; ks < 2; ++ks){
      const int kb = ks * 64 + lq * 16;
      const int ra = rf * 16 + lr;
      bf16x8 af = *(const bf16x8*)((const char*)As + ra * 128 + (kb ^ ((ra & 7) << 4)));
      #pragma unroll
      for (int fc = 0; fc < 4; ++fc){
        int rb = ch * 64 + fc * 16 + lr;
        bf16x8 bf = *(const bf16x8*)((const char*)Bs + rb * 128 + (kb ^ ((rb & 7) << 4)));
        acc[fc] = __builtin_amdgcn_mfma_f32_16x16x32_bf16(af, bf, acc[fc], 0, 0, 0);
      }
    }
    BAR();
  }
  #pragma unroll
  for (int fc = 0; fc < 4; ++fc){
    int col = ch * 64 + fc * 16 + lr;
    float bv = b1[col];
    #pragma unroll
    for (int j = 0; j < 4; ++j){
      int rr = rf * 16 + lq * 4 + j;
      float v = fmaxf(acc[fc][j] + bv, 0.f);
      *(u16*)((char*)Hs + rr * 512 + ((col * 2) ^ ((rr & 7) << 4))) = f2b(v);
    }
  }
  __syncthreads();
  const int rf2 = w & 1, cp = w >> 1;
  f32x4 acc2 = {};
  #pragma unroll
  for (int ks2 = 0; ks2 < 8; ++ks2){
    int rr = rf2 * 16 + lr;
    int kb2 = ks2 * 64 + lq * 16;
    bf16x8 af2 = *(const bf16x8*)((const char*)Hs + rr * 512 + (kb2 ^ ((rr & 7) << 4)));
    bf16x8 w2 = *(const bf16x8*)(W2T + (size_t)(cp * 16 + lr) * 256 + ks2 * 32 + lq * 8);
    acc2 = __builtin_amdgcn_mfma_f32_16x16x32_bf16(af2, w2, acc2, 0, 0, 0);
  }
  {
    int col = cp * 16 + lr;
    float bv = b2[col];
    #pragma unroll
    for (int j = 0; j < 4; ++j){
      int rr = m0 + rf2 * 16 + lq * 4 + j;
      Obase[(size_t)rr * 64 + col] = acc2[j] + bv;
    }
  }
}

// =================== k_mixgru: MFMA cosine dots + mix + GRU =================
// 512 blocks x 32 rows x 512 thr. Dots via fp8 MFMA over gathered concept
// rows staged with global_load_lds (pre-swizzled source, rule #21).
__global__ __launch_bounds__(512) void k_mixgru(
    const u8* __restrict__ qb8, const u8* __restrict__ cb8,
    const float* __restrict__ qn, const float* __restrict__ cn,
    const int* __restrict__ rci, const int* __restrict__ filt,
    const float* __restrict__ redq, const float* __restrict__ redc,
    const float* __restrict__ h, const float* __restrict__ emb,
    const float* __restrict__ op, const float* __restrict__ Wp,
    const float* __restrict__ bp, const u16* __restrict__ WxhT,
    const float* __restrict__ bxh, float* __restrict__ prob_out,
    float* __restrict__ outh)
{
  __shared__ char SM[56320];
  u16*   XH   = (u16*)SM;                 // [32 rows] stride 640 B, swizzled
  float* DOTS = (float*)(SM + 20480);     // [32][8]
  int*   SIDX = (int*)(SM + 21504);       // [256]
  int*   SFLT = (int*)(SM + 22528);       // [256]
  u8*    Cs   = (u8*)(SM + 23552);        // [256][64] fp8 (aliases Bs)
  u8*    Qs8  = (u8*)(SM + 23552 + 16384);// [32][64] fp8
  u16*   Bs   = (u16*)(SM + 23552);       // [256][64] bf16 (GRU phase)
  const int tid = threadIdx.x;
  const int lane = tid & 63;
  const int w = tid >> 6;
  const int m0 = blockIdx.x << 5;

  if (tid < 256) SIDX[tid] = rci[m0 * MAXC_ + tid];
  else           SFLT[tid - 256] = filt[m0 * MAXC_ + (tid - 256)];
  __syncthreads();

  // ---------- phase 1: dots[32 rows][256 slots] via fp8 MFMA ----------
  // LDS linear [slot][64B]; source pre-swizzled: chunk q4 = q4pos ^ sw(slot).
  const int R = w >> 2;                     // rowtile
  const int cc0 = (w & 3) * 2;              // first coltile (within rowtile)
  f32x4 dacc[2] = {};
  for (int kt = 0; kt < 16; ++kt){
    #pragma unroll
    for (int i = 0; i < 2; ++i){
      int e = i * 512 + tid;                // 0..1023
      int slot = e >> 2, q4 = e & 3;
      int sw = (slot ^ (slot >> 2)) & 3;
      gload16(cb8 + (size_t)SIDX[slot] * TDIM_ + kt * 64 + ((q4 ^ sw) << 4),
              Cs + e * 16);
    }
    if (tid < 128){
      int slot = tid >> 2, q4 = tid & 3;
      int sw = (slot ^ (slot >> 2)) & 3;
      gload16(qb8 + (size_t)(m0 + slot) * TDIM_ + kt * 64 + ((q4 ^ sw) << 4),
              Qs8 + tid * 16);
    }
    VMW(0);
    BAR();
    #pragma unroll
    for (int ks = 0; ks < 2; ++ks){
      const int h8 = ks * 4 + (lane >> 4);  // 8B chunk index 0..7
      const int arow = R * 16 + (lane & 15);
      const int asw = (arow ^ (arow >> 2)) & 3;
      i64 a = *(const i64*)(Qs8 + arow * 64 + (((h8 >> 1) ^ asw) << 4) + (h8 & 1) * 8);
      #pragma unroll
      for (int t = 0; t < 2; ++t){
        int slot = (R * 8 + cc0 + t) * 16 + (lane & 15);
        int bsw = (slot ^ (slot >> 2)) & 3;
        i64 bfr = *(const i64*)(Cs + slot * 64 + (((h8 >> 1) ^ bsw) << 4) + (h8 & 1) * 8);
        dacc[t] = __builtin_amdgcn_mfma_f32_16x16x32_fp8_fp8(a, bfr, dacc[t], 0, 0, 0);
      }
    }
    BAR();
  }
  // extract block-diagonal dots -> DOTS[row][m]
  #pragma unroll
  for (int t = 0; t < 2; ++t){
    const int cc = cc0 + t;
    const int col = lane & 15;
    #pragma unroll
    for (int j = 0; j < 4; ++j){
      int tr = (lane >> 4) * 4 + j;
      if (tr == 2 * cc && col < 8)       DOTS[(R * 16 + tr) * 8 + col] = dacc[t][j];
      if (tr == 2 * cc + 1 && col >= 8)  DOTS[(R * 16 + tr) * 8 + col - 8] = dacc[t][j];
    }
  }
  // GRU B tile 0 staging flies under the per-row phase (Cs dead after BAR)
  auto stageB = [&](int kt){
    #pragma unroll
    for (int i = 0; i < 4; ++i){
      int cc = i * 512 + tid;
      int r2 = cc >> 3, s2 = cc & 7;
      gload16(WxhT + (size_t)r2 * 320 + kt * 64 + ((s2 ^ (r2 & 7)) << 3), &Bs[cc * 8]);
    }
  };
  __syncthreads();
  stageB(0);

  // ---------- phase 2: softmax / rep / predictor / xh (4 rows per wave) ----
  for (int i = 0; i < 4; ++i){
    const int r = w * 4 + i;
    const int b = m0 + r;
    int idxm[MAXC_];
    #pragma unroll
    for (int m = 0; m < MAXC_; ++m) idxm[m] = SIDX[r * MAXC_ + m];
    const float qnb = qn[b];
    float sv[MAXC_]; float mx = -3.0e38f;
    #pragma unroll
    for (int m = 0; m < MAXC_; ++m){
      float dnm = fmaxf(qnb * cn[idxm[m]], 1e-8f);
      float s = (SFLT[r * MAXC_ + m] == 0) ? -1e9f
              : DOTS[r * 8 + m] * (1.f / 1024.f) / dnm;
      sv[m] = s; mx = fmaxf(mx, s);
    }
    float se = 0.f;
    #pragma unroll
    for (int m = 0; m < MAXC_; ++m){ sv[m] = __expf(sv[m] - mx); se += sv[m]; }
    const float inv = 1.f / se;
    float rep = 0.f;
    #pragma unroll
    for (int m = 0; m < MAXC_; ++m) rep += sv[m] * redc[(size_t)idxm[m] * D_ + lane];
    rep *= inv;
    const float v0 = redq[(size_t)b * D_ + lane];
    const float hv = h[(size_t)b * D_ + lane];
    const float e0 = emb[(size_t)b * 128 + lane];
    const float e1 = emb[(size_t)b * 128 + 64 + lane];
    float p = hv * Wp[lane] + v0 * Wp[64 + lane] + rep * Wp[128 + lane]
            + e0 * Wp[192 + lane] + e1 * Wp[256 + lane];
    p = wsum(p);
    if (lane == 0) prob_out[b] = p + bp[0];
    const float o = op[b], om = 1.f - o;
    auto xst = [&](int col, float v){
      *(u16*)((char*)XH + r * 640 + ((col * 2) ^ ((r & 7) << 4))) = f2b(v);
    };
    xst(lane,        v0 * o  + e0 * om);
    xst(64 + lane,   rep * o + e1 * om);
    xst(128 + lane,  v0 * om + e0 * o);
    xst(192 + lane,  rep * om + e1 * o);
    xst(256 + lane,  hv);
  }
  __syncthreads();

  // ---------- phase 3: GRU GEMM [32,320]@[320,256] (exact R8) --------------
  const int lr = lane & 15, lq = lane >> 4;
  const int rh = w & 1, cc2 = w >> 1;
  f32x4 acc[4] = {};
  for (int kt = 0; kt < 5; ++kt){
    VMW(0);
    BAR();
    #pragma unroll
    for (int ks = 0; ks < 2; ++ks){
      const int kb = ks * 64 + lq * 16;
      int rra = rh * 16 + lr;
      bf16x8 af = *(const bf16x8*)((const char*)XH + rra * 640 +
                                   ((kt * 128 + kb) ^ ((rra & 7) << 4)));
      bf16x8 bfr[4];
      #pragma unroll
      for (int fc = 0; fc < 4; ++fc){
        int rr = cc2 * 64 + fc * 16 + lr;
        bfr[fc] = *(const bf16x8*)((const char*)Bs + rr * 128 + (kb ^ ((rr & 7) << 4)));
      }
      #pragma unroll
      for (int fc = 0; fc < 4; ++fc)
        acc[fc] = __builtin_amdgcn_mfma_f32_16x16x32_bf16(af, bfr[fc], acc[fc], 0, 0, 0);
    }
    BAR();
    if (kt < 4) stageB(kt + 1);
  }
  const int d = cc2 * 16 + lr;
  float bg[4];
  #pragma unroll
  for (int g = 0; g < 4; ++g) bg[g] = bxh[cc2 * 64 + g * 16 + lr];
  #pragma unroll
  for (int j = 0; j < 4; ++j){
    float rv = sigf(acc[0][j] + bg[0]);
    float zv = sigf(acc[1][j] + bg[1]);
    float nv = tanhf(acc[2][j] + bg[2] + rv * (acc[3][j] + bg[3]));
    int rr = m0 + rh * 16 + lq * 4 + j;
    float hv = h[(size_t)rr * 64 + d];
    outh[(size_t)rr * 64 + d] = (1.f - zv) * nv + zv * hv;
  }
}

extern "C" void kernel_launch(void* const* d_in, const int* in_sizes, int n_in,
                              void* d_out, int out_size, void* d_ws, size_t ws_size,
                              hipStream_t stream) {
  const int*   prob_ids = (const int*)  d_in[0];
  const int*   rci      = (const int*)  d_in[1];
  const int*   filt     = (const int*)  d_in[2];
  const float* h        = (const float*)d_in[3];
  const float* emb      = (const float*)d_in[4];
  const float* op       = (const float*)d_in[5];
  const float* ex       = (const float*)d_in[6];
  const float* con      = (const float*)d_in[7];
  const float* W1       = (const float*)d_in[8];
  const float* b1       = (const float*)d_in[9];
  const float* W2       = (const float*)d_in[10];
  const float* b2       = (const float*)d_in[11];
  const float* Wp       = (const float*)d_in[12];
  const float* bp       = (const float*)d_in[13];
  const float* Wx       = (const float*)d_in[14];
  const float* Wh       = (const float*)d_in[15];
  const float* bx       = (const float*)d_in[16];
  const float* bh       = (const float*)d_in[17];
  float* out = (float*)d_out;

  char* w = (char*)d_ws;
  size_t off = 0;
  auto alloc = [&](size_t bytes){ size_t o = off; off = (off + bytes + 255) & ~(size_t)255; return o; };
  u16*   qb   = (u16*)  (w + alloc((size_t)B_ * TDIM_ * 2));      // 32 MB
  u8*    qb8  = (u8*)   (w + alloc((size_t)B_ * TDIM_));          // 16 MB
  u16*   cb   = (u16*)  (w + alloc((size_t)NCONP_ * TDIM_ * 2));  // 4 MB
  u8*    cb8  = (u8*)   (w + alloc((size_t)NCONP_ * TDIM_));      // 2 MB
  float* qn   = (float*)(w + alloc((size_t)B_ * 4));
  float* cn   = (float*)(w + alloc((size_t)NCONP_ * 4));
  float* redq = (float*)(w + alloc((size_t)B_ * D_ * 4));         // 4 MB
  float* redc = (float*)(w + alloc((size_t)NCONP_ * D_ * 4));
  u16*   W1T  = (u16*)  (w + alloc((size_t)HID_ * TDIM_ * 2));
  u16*   W2T  = (u16*)  (w + alloc((size_t)D_ * HID_ * 2));
  u16*   WxhT = (u16*)  (w + alloc((size_t)256 * 320 * 2));
  float* bxh  = (float*)(w + alloc((size_t)256 * 4));

  k_prep<<<6017, 256, 0, stream>>>(ex, prob_ids, con, W1, W2, Wx, Wh, bx, bh,
                                   qb, qb8, qn, cb, cb8, cn, W1T, W2T, WxhT, bxh);
  k_mlp<<<576, 512, 0, stream>>>(qb, cb, W1T, b1, W2T, b2, redq, redc);
  k_mixgru<<<512, 512, 0, stream>>>(qb8, cb8, qn, cn, rci, filt, redq, redc,
                                    h, emb, op, Wp, bp, WxhT, bxh, out, out + B_);
}

// Round 17
// 80.240 us; speedup vs baseline: 1.2306x; 1.0621x over previous
//
#include <hip/hip_runtime.h>
#include <cstdint>
#include <cstddef>

typedef unsigned short u16;
typedef unsigned char u8;
typedef long long i64;
typedef unsigned long long u64;
typedef __bf16 bf16x8 __attribute__((ext_vector_type(8)));
typedef float f32x4 __attribute__((ext_vector_type(4)));
typedef float f32x2 __attribute__((ext_vector_type(2)));
typedef u16 u16x4 __attribute__((ext_vector_type(4)));
typedef u16 u16x8 __attribute__((ext_vector_type(8)));

#define B_ 16384
#define D_ 64
#define MAXC_ 8
#define NCON_ 2000
#define NCONP_ 2048
#define TDIM_ 1024
#define HID_ 256

#define VMW(n) asm volatile("s_waitcnt vmcnt(" #n ")" ::: "memory")
#define LGKM0 asm volatile("s_waitcnt lgkmcnt(0)" ::: "memory")
#define BAR() __builtin_amdgcn_s_barrier()

__device__ inline u16 f2b(float f){
  unsigned u = __float_as_uint(f);
  u += 0x7fffu + ((u >> 16) & 1u);
  return (u16)(u >> 16);
}
__device__ inline float b2f(u16 u){ return __uint_as_float(((unsigned)u) << 16); }

__device__ inline unsigned pk2fp8(float a, float b){
  return (unsigned)__builtin_amdgcn_cvt_pk_fp8_f32(a, b, 0, false);
}
template<bool HI>
__device__ inline f32x2 unpk_fp8(unsigned v){
  return __builtin_amdgcn_cvt_pk_f32_fp8(v, HI);
}

__device__ inline void gload16(const void* g, void* l){
  __builtin_amdgcn_global_load_lds((const __attribute__((address_space(1))) unsigned*)g,
                                   (__attribute__((address_space(3))) unsigned*)l, 16, 0, 0);
}

__device__ inline float wsum(float v){
  #pragma unroll
  for (int o = 32; o; o >>= 1) v += __shfl_xor(v, o);
  return v;
}
__device__ inline float sigf(float x){ return 1.f / (1.f + __expf(-x)); }

// =================== k_prep: fp8-only q/c + weights =========================
__global__ __launch_bounds__(256) void k_prep(
    const float* __restrict__ ex, const int* __restrict__ pid,
    const float* __restrict__ con,
    const float* __restrict__ W1, const float* __restrict__ W2,
    const float* __restrict__ Wx, const float* __restrict__ Wh,
    const float* __restrict__ bx, const float* __restrict__ bh,
    u8* __restrict__ qb8, float* __restrict__ qn,
    u8* __restrict__ cb8, float* __restrict__ cn,
    u16* __restrict__ W1T, u16* __restrict__ W2T, u16* __restrict__ WxhT,
    float* __restrict__ bxh)
{
  const int bid = blockIdx.x, tid = threadIdx.x;
  const int lane = tid & 63;
  if (bid < 4096){                                  // ---- q gather ----
    const int b = bid * 4 + (tid >> 6);
    const float* src = ex + (size_t)pid[b] * TDIM_;
    u8* dst8 = qb8 + (size_t)b * TDIM_;
    float ss = 0.f;
    #pragma unroll
    for (int c = 0; c < 4; ++c){
      float4 v = *(const float4*)(src + c * 256 + lane * 4);
      ss += v.x*v.x + v.y*v.y + v.z*v.z + v.w*v.w;
      unsigned lo = pk2fp8(v.x * 32.f, v.y * 32.f);
      unsigned hi = pk2fp8(v.z * 32.f, v.w * 32.f);
      *(unsigned*)(dst8 + c * 256 + lane * 4) = (lo & 0xffffu) | (hi << 16);
    }
    ss = wsum(ss);
    if (lane == 0) qn[b] = sqrtf(ss);
  } else if (bid < 4608){                           // ---- concepts ----
    const int r = (bid - 4096) * 4 + (tid >> 6);
    u8* dst8 = cb8 + (size_t)r * TDIM_;
    if (r < NCON_){
      const float* src = con + (size_t)r * TDIM_;
      float ss = 0.f;
      #pragma unroll
      for (int c = 0; c < 4; ++c){
        float4 v = *(const float4*)(src + c * 256 + lane * 4);
        ss += v.x*v.x + v.y*v.y + v.z*v.z + v.w*v.w;
        unsigned lo = pk2fp8(v.x * 32.f, v.y * 32.f);
        unsigned hi = pk2fp8(v.z * 32.f, v.w * 32.f);
        *(unsigned*)(dst8 + c * 256 + lane * 4) = (lo & 0xffffu) | (hi << 16);
      }
      ss = wsum(ss);
      if (lane == 0) cn[r] = sqrtf(ss);
    } else {
      #pragma unroll
      for (int c = 0; c < 4; ++c)
        *(unsigned*)(dst8 + c * 256 + lane * 4) = 0u;
    }
  } else {                                          // ---- weights ----
    int gid = (bid - 4608) * 256 + tid;
    if (gid < 262144){                       // W1T: n*1024 + k
      int n = gid >> 10, k = gid & 1023;
      W1T[gid] = f2b(W1[(size_t)k * 256 + n]);
    } else if (gid < 278528){                // W2T: n*256 + k
      int t = gid - 262144;
      int n = t >> 8, k = t & 255;
      W2T[t] = f2b(W2[(size_t)k * 64 + n]);
    } else if (gid < 360448){                // WxhT: c*320 + k, gate-interleaved
      int t = gid - 278528;
      int c = t / 320, k = t % 320;
      int g = (c >> 4) & 3;
      int d = (c >> 6) * 16 + (c & 15);
      float v = 0.f;
      if (k < 256){
        if (g == 0)      v = Wx[(size_t)k * 192 + d];
        else if (g == 1) v = Wx[(size_t)k * 192 + 64 + d];
        else if (g == 2) v = Wx[(size_t)k * 192 + 128 + d];
      } else {
        int kh = k - 256;
        if (g == 0)      v = Wh[(size_t)kh * 192 + d];
        else if (g == 1) v = Wh[(size_t)kh * 192 + 64 + d];
        else if (g == 3) v = Wh[(size_t)kh * 192 + 128 + d];
      }
      WxhT[t] = f2b(v);
    } else if (gid < 360704){                // bxh
      int c = gid - 360448;
      int g = (c >> 4) & 3;
      int d = (c >> 6) * 16 + (c & 15);
      float v;
      if (g == 0)      v = bx[d] + bh[d];
      else if (g == 1) v = bx[64 + d] + bh[64 + d];
      else if (g == 2) v = bx[128 + d];
      else             v = bh[128 + d];
      bxh[c] = v;
    }
  }
}

// =================== k_mlp: A reg-staged from fp8 (exact bf16 decode) =======
// BM=32, 576 blocks x 512 thr. GEMM body identical to R8; A-tile decoded
// fp8->bf16 in registers (exact), x32 scale folded into epilogue.
__global__ __launch_bounds__(512) void k_mlp(
    const u8* __restrict__ qb8, const u8* __restrict__ cb8,
    const u16* __restrict__ W1T, const float* __restrict__ b1,
    const u16* __restrict__ W2T, const float* __restrict__ b2,
    float* __restrict__ redq, float* __restrict__ redc)
{
  __shared__ u16 As[32 * 64];      // 4 KB
  __shared__ u16 Bs[256 * 64];     // 32 KB
  __shared__ u16 Hs[32 * 256];     // 16 KB
  const int tid = threadIdx.x;
  const int lane = tid & 63;
  const int w = tid >> 6;
  const int lr = lane & 15, lq = lane >> 4;
  const bool qside = blockIdx.x < 512;
  const u8* Abase = qside ? qb8 : cb8;
  float* Obase = qside ? redq : redc;
  const int m0 = (qside ? (int)blockIdx.x : ((int)blockIdx.x - 512)) << 5;
  const int rf = w & 1, ch = w >> 1;
  const int arow = tid >> 3, asub = tid & 7;

  f32x4 acc[4] = {};
  for (int kt = 0; kt < 16; ++kt){
    if (tid < 256){
      u64 pk8 = *(const u64*)(Abase + (size_t)(m0 + arow) * 1024 + kt * 64 + (asub << 3));
      f32x2 p0 = unpk_fp8<false>((unsigned)pk8);
      f32x2 p1 = unpk_fp8<true >((unsigned)pk8);
      f32x2 p2 = unpk_fp8<false>((unsigned)(pk8 >> 32));
      f32x2 p3 = unpk_fp8<true >((unsigned)(pk8 >> 32));
      u16x8 o = { (u16)(__float_as_uint(p0[0]) >> 16), (u16)(__float_as_uint(p0[1]) >> 16),
                  (u16)(__float_as_uint(p1[0]) >> 16), (u16)(__float_as_uint(p1[1]) >> 16),
                  (u16)(__float_as_uint(p2[0]) >> 16), (u16)(__float_as_uint(p2[1]) >> 16),
                  (u16)(__float_as_uint(p3[0]) >> 16), (u16)(__float_as_uint(p3[1]) >> 16) };
      *(u16x8*)((char*)As + arow * 128 + ((asub << 4) ^ ((arow & 7) << 4))) = o;
    }
    #pragma unroll
    for (int i = 0; i < 4; ++i){
      int cc = i * 512 + tid;
      int r2 = cc >> 3, s2 = cc & 7;
      gload16(W1T + (size_t)r2 * 1024 + kt * 64 + ((s2 ^ (r2 & 7)) << 3), &Bs[cc * 8]);
    }
    VMW(0);
    LGKM0;
    BAR();
    #pragma unroll
    for (int ks = 0; ks < 2; ++ks){
      const int kb = ks * 64 + lq * 16;
      const int ra = rf * 16 + lr;
      bf16x8 af = *(const bf16x8*)((const char*)As + ra * 128 + (kb ^ ((ra & 7) << 4)));
      #pragma unroll
      for (int fc = 0; fc < 4; ++fc){
        int rb = ch * 64 + fc * 16 + lr;
        bf16x8 bf = *(const bf16x8*)((const char*)Bs + rb * 128 + (kb ^ ((rb & 7) << 4)));
        acc[fc] = __builtin_amdgcn_mfma_f32_16x16x32_bf16(af, bf, acc[fc], 0, 0, 0);
      }
    }
    BAR();
  }
  #pragma unroll
  for (int fc = 0; fc < 4; ++fc){
    int col = ch * 64 + fc * 16 + lr;
    float bv = b1[col];
    #pragma unroll
    for (int j = 0; j < 4; ++j){
      int rr = rf * 16 + lq * 4 + j;
      float v = fmaxf(acc[fc][j] * (1.f / 32.f) + bv, 0.f);
      *(u16*)((char*)Hs + rr * 512 + ((col * 2) ^ ((rr & 7) << 4))) = f2b(v);
    }
  }
  __syncthreads();
  const int rf2 = w & 1, cp = w >> 1;
  f32x4 acc2 = {};
  #pragma unroll
  for (int ks2 = 0; ks2 < 8; ++ks2){
    int rr = rf2 * 16 + lr;
    int kb2 = ks2 * 64 + lq * 16;
    bf16x8 af2 = *(const bf16x8*)((const char*)Hs + rr * 512 + (kb2 ^ ((rr & 7) << 4)));
    bf16x8 w2 = *(const bf16x8*)(W2T + (size_t)(cp * 16 + lr) * 256 + ks2 * 32 + lq * 8);
    acc2 = __builtin_amdgcn_mfma_f32_16x16x32_bf16(af2, w2, acc2, 0, 0, 0);
  }
  {
    int col = cp * 16 + lr;
    float bv = b2[col];
    #pragma unroll
    for (int j = 0; j < 4; ++j){
      int rr = m0 + rf2 * 16 + lq * 4 + j;
      Obase[(size_t)rr * 64 + col] = acc2[j] + bv;
    }
  }
}

// =================== k_mixgru (exact R16): MFMA dots + mix + GRU ============
__global__ __launch_bounds__(512) void k_mixgru(
    const u8* __restrict__ qb8, const u8* __restrict__ cb8,
    const float* __restrict__ qn, const float* __restrict__ cn,
    const int* __restrict__ rci, const int* __restrict__ filt,
    const float* __restrict__ redq, const float* __restrict__ redc,
    const float* __restrict__ h, const float* __restrict__ emb,
    const float* __restrict__ op, const float* __restrict__ Wp,
    const float* __restrict__ bp, const u16* __restrict__ WxhT,
    const float* __restrict__ bxh, float* __restrict__ prob_out,
    float* __restrict__ outh)
{
  __shared__ char SM[56320];
  u16*   XH   = (u16*)SM;                 // [32 rows] stride 640 B, swizzled
  float* DOTS = (float*)(SM + 20480);     // [32][8]
  int*   SIDX = (int*)(SM + 21504);       // [256]
  int*   SFLT = (int*)(SM + 22528);       // [256]
  u8*    Cs   = (u8*)(SM + 23552);        // [256][64] fp8 (aliases Bs)
  u8*    Qs8  = (u8*)(SM + 23552 + 16384);// [32][64] fp8
  u16*   Bs   = (u16*)(SM + 23552);       // [256][64] bf16 (GRU phase)
  const int tid = threadIdx.x;
  const int lane = tid & 63;
  const int w = tid >> 6;
  const int m0 = blockIdx.x << 5;

  if (tid < 256) SIDX[tid] = rci[m0 * MAXC_ + tid];
  else           SFLT[tid - 256] = filt[m0 * MAXC_ + (tid - 256)];
  __syncthreads();

  // ---------- phase 1: dots[32 rows][256 slots] via fp8 MFMA ----------
  const int R = w >> 2;
  const int cc0 = (w & 3) * 2;
  f32x4 dacc[2] = {};
  for (int kt = 0; kt < 16; ++kt){
    #pragma unroll
    for (int i = 0; i < 2; ++i){
      int e = i * 512 + tid;
      int slot = e >> 2, q4 = e & 3;
      int sw = (slot ^ (slot >> 2)) & 3;
      gload16(cb8 + (size_t)SIDX[slot] * TDIM_ + kt * 64 + ((q4 ^ sw) << 4),
              Cs + e * 16);
    }
    if (tid < 128){
      int slot = tid >> 2, q4 = tid & 3;
      int sw = (slot ^ (slot >> 2)) & 3;
      gload16(qb8 + (size_t)(m0 + slot) * TDIM_ + kt * 64 + ((q4 ^ sw) << 4),
              Qs8 + tid * 16);
    }
    VMW(0);
    BAR();
    #pragma unroll
    for (int ks = 0; ks < 2; ++ks){
      const int h8 = ks * 4 + (lane >> 4);
      const int arow = R * 16 + (lane & 15);
      const int asw = (arow ^ (arow >> 2)) & 3;
      i64 a = *(const i64*)(Qs8 + arow * 64 + (((h8 >> 1) ^ asw) << 4) + (h8 & 1) * 8);
      #pragma unroll
      for (int t = 0; t < 2; ++t){
        int slot = (R * 8 + cc0 + t) * 16 + (lane & 15);
        int bsw = (slot ^ (slot >> 2)) & 3;
        i64 bfr = *(const i64*)(Cs + slot * 64 + (((h8 >> 1) ^ bsw) << 4) + (h8 & 1) * 8);
        dacc[t] = __builtin_amdgcn_mfma_f32_16x16x32_fp8_fp8(a, bfr, dacc[t], 0, 0, 0);
      }
    }
    BAR();
  }
  #pragma unroll
  for (int t = 0; t < 2; ++t){
    const int cc = cc0 + t;
    const int col = lane & 15;
    #pragma unroll
    for (int j = 0; j < 4; ++j){
      int tr = (lane >> 4) * 4 + j;
      if (tr == 2 * cc && col < 8)       DOTS[(R * 16 + tr) * 8 + col] = dacc[t][j];
      if (tr == 2 * cc + 1 && col >= 8)  DOTS[(R * 16 + tr) * 8 + col - 8] = dacc[t][j];
    }
  }
  auto stageB = [&](int kt){
    #pragma unroll
    for (int i = 0; i < 4; ++i){
      int cc = i * 512 + tid;
      int r2 = cc >> 3, s2 = cc & 7;
      gload16(WxhT + (size_t)r2 * 320 + kt * 64 + ((s2 ^ (r2 & 7)) << 3), &Bs[cc * 8]);
    }
  };
  __syncthreads();
  stageB(0);

  // ---------- phase 2: softmax / rep / predictor / xh ----------
  for (int i = 0; i < 4; ++i){
    const int r = w * 4 + i;
    const int b = m0 + r;
    int idxm[MAXC_];
    #pragma unroll
    for (int m = 0; m < MAXC_; ++m) idxm[m] = SIDX[r * MAXC_ + m];
    const float qnb = qn[b];
    float sv[MAXC_]; float mx = -3.0e38f;
    #pragma unroll
    for (int m = 0; m < MAXC_; ++m){
      float dnm = fmaxf(qnb * cn[idxm[m]], 1e-8f);
      float s = (SFLT[r * MAXC_ + m] == 0) ? -1e9f
              : DOTS[r * 8 + m] * (1.f / 1024.f) / dnm;
      sv[m] = s; mx = fmaxf(mx, s);
    }
    float se = 0.f;
    #pragma unroll
    for (int m = 0; m < MAXC_; ++m){ sv[m] = __expf(sv[m] - mx); se += sv[m]; }
    const float inv = 1.f / se;
    float rep = 0.f;
    #pragma unroll
    for (int m = 0; m < MAXC_; ++m) rep += sv[m] * redc[(size_t)idxm[m] * D_ + lane];
    rep *= inv;
    const float v0 = redq[(size_t)b * D_ + lane];
    const float hv = h[(size_t)b * D_ + lane];
    const float e0 = emb[(size_t)b * 128 + lane];
    const float e1 = emb[(size_t)b * 128 + 64 + lane];
    float p = hv * Wp[lane] + v0 * Wp[64 + lane] + rep * Wp[128 + lane]
            + e0 * Wp[192 + lane] + e1 * Wp[256 + lane];
    p = wsum(p);
    if (lane == 0) prob_out[b] = p + bp[0];
    const float o = op[b], om = 1.f - o;
    auto xst = [&](int col, float v){
      *(u16*)((char*)XH + r * 640 + ((col * 2) ^ ((r & 7) << 4))) = f2b(v);
    };
    xst(lane,        v0 * o  + e0 * om);
    xst(64 + lane,   rep * o + e1 * om);
    xst(128 + lane,  v0 * om + e0 * o);
    xst(192 + lane,  rep * om + e1 * o);
    xst(256 + lane,  hv);
  }
  __syncthreads();

  // ---------- phase 3: GRU GEMM [32,320]@[320,256] ----------
  const int lr = lane & 15, lq = lane >> 4;
  const int rh = w & 1, cc2 = w >> 1;
  f32x4 acc[4] = {};
  for (int kt = 0; kt < 5; ++kt){
    VMW(0);
    BAR();
    #pragma unroll
    for (int ks = 0; ks < 2; ++ks){
      const int kb = ks * 64 + lq * 16;
      int rra = rh * 16 + lr;
      bf16x8 af = *(const bf16x8*)((const char*)XH + rra * 640 +
                                   ((kt * 128 + kb) ^ ((rra & 7) << 4)));
      bf16x8 bfr[4];
      #pragma unroll
      for (int fc = 0; fc < 4; ++fc){
        int rr = cc2 * 64 + fc * 16 + lr;
        bfr[fc] = *(const bf16x8*)((const char*)Bs + rr * 128 + (kb ^ ((rr & 7) << 4)));
      }
      #pragma unroll
      for (int fc = 0; fc < 4; ++fc)
        acc[fc] = __builtin_amdgcn_mfma_f32_16x16x32_bf16(af, bfr[fc], acc[fc], 0, 0, 0);
    }
    BAR();
    if (kt < 4) stageB(kt + 1);
  }
  const int d = cc2 * 16 + lr;
  float bg[4];
  #pragma unroll
  for (int g = 0; g < 4; ++g) bg[g] = bxh[cc2 * 64 + g * 16 + lr];
  #pragma unroll
  for (int j = 0; j < 4; ++j){
    float rv = sigf(acc[0][j] + bg[0]);
    float zv = sigf(acc[1][j] + bg[1]);
    float nv = tanhf(acc[2][j] + bg[2] + rv * (acc[3][j] + bg[3]));
    int rr = m0 + rh * 16 + lq * 4 + j;
    float hv = h[(size_t)rr * 64 + d];
    outh[(size_t)rr * 64 + d] = (1.f - zv) * nv + zv * hv;
  }
}

extern "C" void kernel_launch(void* const* d_in, const int* in_sizes, int n_in,
                              void* d_out, int out_size, void* d_ws, size_t ws_size,
                              hipStream_t stream) {
  const int*   prob_ids = (const int*)  d_in[0];
  const int*   rci      = (const int*)  d_in[1];
  const int*   filt     = (const int*)  d_in[2];
  const float* h        = (const float*)d_in[3];
  const float* emb      = (const float*)d_in[4];
  const float* op       = (const float*)d_in[5];
  const float* ex       = (const float*)d_in[6];
  const float* con      = (const float*)d_in[7];
  const float* W1       = (const float*)d_in[8];
  const float* b1       = (const float*)d_in[9];
  const float* W2       = (const float*)d_in[10];
  const float* b2       = (const float*)d_in[11];
  const float* Wp       = (const float*)d_in[12];
  const float* bp       = (const float*)d_in[13];
  const float* Wx       = (const float*)d_in[14];
  const float* Wh       = (const float*)d_in[15];
  const float* bx       = (const float*)d_in[16];
  const float* bh       = (const float*)d_in[17];
  float* out = (float*)d_out;

  char* w = (char*)d_ws;
  size_t off = 0;
  auto alloc = [&](size_t bytes){ size_t o = off; off = (off + bytes + 255) & ~(size_t)255; return o; };
  u8*    qb8  = (u8*)   (w + alloc((size_t)B_ * TDIM_));          // 16 MB
  u8*    cb8  = (u8*)   (w + alloc((size_t)NCONP_ * TDIM_));      // 2 MB
  float* qn   = (float*)(w + alloc((size_t)B_ * 4));
  float* cn   = (float*)(w + alloc((size_t)NCONP_ * 4));
  float* redq = (float*)(w + alloc((size_t)B_ * D_ * 4));         // 4 MB
  float* redc = (float*)(w + alloc((size_t)NCONP_ * D_ * 4));
  u16*   W1T  = (u16*)  (w + alloc((size_t)HID_ * TDIM_ * 2));
  u16*   W2T  = (u16*)  (w + alloc((size_t)D_ * HID_ * 2));
  u16*   WxhT = (u16*)  (w + alloc((size_t)256 * 320 * 2));
  float* bxh  = (float*)(w + alloc((size_t)256 * 4));

  k_prep<<<6017, 256, 0, stream>>>(ex, prob_ids, con, W1, W2, Wx, Wh, bx, bh,
                                   qb8, qn, cb8, cn, W1T, W2T, WxhT, bxh);
  k_mlp<<<576, 512, 0, stream>>>(qb8, cb8, W1T, b1, W2T, b2, redq, redc);
  k_mixgru<<<512, 512, 0, stream>>>(qb8, cb8, qn, cn, rci, filt, redq, redc,
                                    h, emb, op, Wp, bp, WxhT, bxh, out, out + B_);
}

// Round 18
// 78.135 us; speedup vs baseline: 1.2638x; 1.0269x over previous
//
#include <hip/hip_runtime.h>
#include <cstdint>
#include <cstddef>

typedef unsigned short u16;
typedef unsigned char u8;
typedef long long i64;
typedef unsigned long long u64;
typedef __bf16 bf16x8 __attribute__((ext_vector_type(8)));
typedef float f32x4 __attribute__((ext_vector_type(4)));
typedef float f32x2 __attribute__((ext_vector_type(2)));
typedef u16 u16x4 __attribute__((ext_vector_type(4)));
typedef u16 u16x8 __attribute__((ext_vector_type(8)));

#define B_ 16384
#define D_ 64
#define MAXC_ 8
#define NCON_ 2000
#define NCONP_ 2048
#define TDIM_ 1024
#define HID_ 256

#define VMW(n) asm volatile("s_waitcnt vmcnt(" #n ")" ::: "memory")
#define LGKM0 asm volatile("s_waitcnt lgkmcnt(0)" ::: "memory")
#define BAR() __builtin_amdgcn_s_barrier()

__device__ inline u16 f2b(float f){
  unsigned u = __float_as_uint(f);
  u += 0x7fffu + ((u >> 16) & 1u);
  return (u16)(u >> 16);
}
__device__ inline float b2f(u16 u){ return __uint_as_float(((unsigned)u) << 16); }

__device__ inline unsigned pk2fp8(float a, float b){
  return (unsigned)__builtin_amdgcn_cvt_pk_fp8_f32(a, b, 0, false);
}
template<bool HI>
__device__ inline f32x2 unpk_fp8(unsigned v){
  return __builtin_amdgcn_cvt_pk_f32_fp8(v, HI);
}

__device__ inline void gload16(const void* g, void* l){
  __builtin_amdgcn_global_load_lds((const __attribute__((address_space(1))) unsigned*)g,
                                   (__attribute__((address_space(3))) unsigned*)l, 16, 0, 0);
}

__device__ inline float wsum(float v){
  #pragma unroll
  for (int o = 32; o; o >>= 1) v += __shfl_xor(v, o);
  return v;
}
__device__ inline float sigf(float x){ return 1.f / (1.f + __expf(-x)); }

// =================== k_prep (exact R17): fp8-only q/c + weights =============
__global__ __launch_bounds__(256) void k_prep(
    const float* __restrict__ ex, const int* __restrict__ pid,
    const float* __restrict__ con,
    const float* __restrict__ W1, const float* __restrict__ W2,
    const float* __restrict__ Wx, const float* __restrict__ Wh,
    const float* __restrict__ bx, const float* __restrict__ bh,
    u8* __restrict__ qb8, float* __restrict__ qn,
    u8* __restrict__ cb8, float* __restrict__ cn,
    u16* __restrict__ W1T, u16* __restrict__ W2T, u16* __restrict__ WxhT,
    float* __restrict__ bxh)
{
  const int bid = blockIdx.x, tid = threadIdx.x;
  const int lane = tid & 63;
  if (bid < 4096){                                  // ---- q gather ----
    const int b = bid * 4 + (tid >> 6);
    const float* src = ex + (size_t)pid[b] * TDIM_;
    u8* dst8 = qb8 + (size_t)b * TDIM_;
    float ss = 0.f;
    #pragma unroll
    for (int c = 0; c < 4; ++c){
      float4 v = *(const float4*)(src + c * 256 + lane * 4);
      ss += v.x*v.x + v.y*v.y + v.z*v.z + v.w*v.w;
      unsigned lo = pk2fp8(v.x * 32.f, v.y * 32.f);
      unsigned hi = pk2fp8(v.z * 32.f, v.w * 32.f);
      *(unsigned*)(dst8 + c * 256 + lane * 4) = (lo & 0xffffu) | (hi << 16);
    }
    ss = wsum(ss);
    if (lane == 0) qn[b] = sqrtf(ss);
  } else if (bid < 4608){                           // ---- concepts ----
    const int r = (bid - 4096) * 4 + (tid >> 6);
    u8* dst8 = cb8 + (size_t)r * TDIM_;
    if (r < NCON_){
      const float* src = con + (size_t)r * TDIM_;
      float ss = 0.f;
      #pragma unroll
      for (int c = 0; c < 4; ++c){
        float4 v = *(const float4*)(src + c * 256 + lane * 4);
        ss += v.x*v.x + v.y*v.y + v.z*v.z + v.w*v.w;
        unsigned lo = pk2fp8(v.x * 32.f, v.y * 32.f);
        unsigned hi = pk2fp8(v.z * 32.f, v.w * 32.f);
        *(unsigned*)(dst8 + c * 256 + lane * 4) = (lo & 0xffffu) | (hi << 16);
      }
      ss = wsum(ss);
      if (lane == 0) cn[r] = sqrtf(ss);
    } else {
      #pragma unroll
      for (int c = 0; c < 4; ++c)
        *(unsigned*)(dst8 + c * 256 + lane * 4) = 0u;
    }
  } else {                                          // ---- weights ----
    int gid = (bid - 4608) * 256 + tid;
    if (gid < 262144){                       // W1T: n*1024 + k
      int n = gid >> 10, k = gid & 1023;
      W1T[gid] = f2b(W1[(size_t)k * 256 + n]);
    } else if (gid < 278528){                // W2T: n*256 + k
      int t = gid - 262144;
      int n = t >> 8, k = t & 255;
      W2T[t] = f2b(W2[(size_t)k * 64 + n]);
    } else if (gid < 360448){                // WxhT: c*320 + k, gate-interleaved
      int t = gid - 278528;
      int c = t / 320, k = t % 320;
      int g = (c >> 4) & 3;
      int d = (c >> 6) * 16 + (c & 15);
      float v = 0.f;
      if (k < 256){
        if (g == 0)      v = Wx[(size_t)k * 192 + d];
        else if (g == 1) v = Wx[(size_t)k * 192 + 64 + d];
        else if (g == 2) v = Wx[(size_t)k * 192 + 128 + d];
      } else {
        int kh = k - 256;
        if (g == 0)      v = Wh[(size_t)kh * 192 + d];
        else if (g == 1) v = Wh[(size_t)kh * 192 + 64 + d];
        else if (g == 3) v = Wh[(size_t)kh * 192 + 128 + d];
      }
      WxhT[t] = f2b(v);
    } else if (gid < 360704){                // bxh
      int c = gid - 360448;
      int g = (c >> 4) & 3;
      int d = (c >> 6) * 16 + (c & 15);
      float v;
      if (g == 0)      v = bx[d] + bh[d];
      else if (g == 1) v = bx[64 + d] + bh[64 + d];
      else if (g == 2) v = bx[128 + d];
      else             v = bh[128 + d];
      bxh[c] = v;
    }
  }
}

// =================== k_mlp (exact R17): A reg-staged from fp8 ===============
__global__ __launch_bounds__(512) void k_mlp(
    const u8* __restrict__ qb8, const u8* __restrict__ cb8,
    const u16* __restrict__ W1T, const float* __restrict__ b1,
    const u16* __restrict__ W2T, const float* __restrict__ b2,
    float* __restrict__ redq, float* __restrict__ redc)
{
  __shared__ u16 As[32 * 64];      // 4 KB
  __shared__ u16 Bs[256 * 64];     // 32 KB
  __shared__ u16 Hs[32 * 256];     // 16 KB
  const int tid = threadIdx.x;
  const int lane = tid & 63;
  const int w = tid >> 6;
  const int lr = lane & 15, lq = lane >> 4;
  const bool qside = blockIdx.x < 512;
  const u8* Abase = qside ? qb8 : cb8;
  float* Obase = qside ? redq : redc;
  const int m0 = (qside ? (int)blockIdx.x : ((int)blockIdx.x - 512)) << 5;
  const int rf = w & 1, ch = w >> 1;
  const int arow = tid >> 3, asub = tid & 7;

  f32x4 acc[4] = {};
  for (int kt = 0; kt < 16; ++kt){
    if (tid < 256){
      u64 pk8 = *(const u64*)(Abase + (size_t)(m0 + arow) * 1024 + kt * 64 + (asub << 3));
      f32x2 p0 = unpk_fp8<false>((unsigned)pk8);
      f32x2 p1 = unpk_fp8<true >((unsigned)pk8);
      f32x2 p2 = unpk_fp8<false>((unsigned)(pk8 >> 32));
      f32x2 p3 = unpk_fp8<true >((unsigned)(pk8 >> 32));
      u16x8 o = { (u16)(__float_as_uint(p0[0]) >> 16), (u16)(__float_as_uint(p0[1]) >> 16),
                  (u16)(__float_as_uint(p1[0]) >> 16), (u16)(__float_as_uint(p1[1]) >> 16),
                  (u16)(__float_as_uint(p2[0]) >> 16), (u16)(__float_as_uint(p2[1]) >> 16),
                  (u16)(__float_as_uint(p3[0]) >> 16), (u16)(__float_as_uint(p3[1]) >> 16) };
      *(u16x8*)((char*)As + arow * 128 + ((asub << 4) ^ ((arow & 7) << 4))) = o;
    }
    #pragma unroll
    for (int i = 0; i < 4; ++i){
      int cc = i * 512 + tid;
      int r2 = cc >> 3, s2 = cc & 7;
      gload16(W1T + (size_t)r2 * 1024 + kt * 64 + ((s2 ^ (r2 & 7)) << 3), &Bs[cc * 8]);
    }
    VMW(0);
    LGKM0;
    BAR();
    #pragma unroll
    for (int ks = 0; ks < 2; ++ks){
      const int kb = ks * 64 + lq * 16;
      const int ra = rf * 16 + lr;
      bf16x8 af = *(const bf16x8*)((const char*)As + ra * 128 + (kb ^ ((ra & 7) << 4)));
      #pragma unroll
      for (int fc = 0; fc < 4; ++fc){
        int rb = ch * 64 + fc * 16 + lr;
        bf16x8 bf = *(const bf16x8*)((const char*)Bs + rb * 128 + (kb ^ ((rb & 7) << 4)));
        acc[fc] = __builtin_amdgcn_mfma_f32_16x16x32_bf16(af, bf, acc[fc], 0, 0, 0);
      }
    }
    BAR();
  }
  #pragma unroll
  for (int fc = 0; fc < 4; ++fc){
    int col = ch * 64 + fc * 16 + lr;
    float bv = b1[col];
    #pragma unroll
    for (int j = 0; j < 4; ++j){
      int rr = rf * 16 + lq * 4 + j;
      float v = fmaxf(acc[fc][j] * (1.f / 32.f) + bv, 0.f);
      *(u16*)((char*)Hs + rr * 512 + ((col * 2) ^ ((rr & 7) << 4))) = f2b(v);
    }
  }
  __syncthreads();
  const int rf2 = w & 1, cp = w >> 1;
  f32x4 acc2 = {};
  #pragma unroll
  for (int ks2 = 0; ks2 < 8; ++ks2){
    int rr = rf2 * 16 + lr;
    int kb2 = ks2 * 64 + lq * 16;
    bf16x8 af2 = *(const bf16x8*)((const char*)Hs + rr * 512 + (kb2 ^ ((rr & 7) << 4)));
    bf16x8 w2 = *(const bf16x8*)(W2T + (size_t)(cp * 16 + lr) * 256 + ks2 * 32 + lq * 8);
    acc2 = __builtin_amdgcn_mfma_f32_16x16x32_bf16(af2, w2, acc2, 0, 0, 0);
  }
  {
    int col = cp * 16 + lr;
    float bv = b2[col];
    #pragma unroll
    for (int j = 0; j < 4; ++j){
      int rr = m0 + rf2 * 16 + lq * 4 + j;
      Obase[(size_t)rr * 64 + col] = acc2[j] + bv;
    }
  }
}

// =================== k_mixgru: dbuf'd MFMA dots + mix + GRU =================
// LDS map: [0,32768) QsF (phase1) / XH+DOTS (phase2+3); [32768,33792) SIDX;
// [33792,34816) SFLT; [34816,67584) Cs[2] (phase1) / Bs (phase3).
__global__ __launch_bounds__(512) void k_mixgru(
    const u8* __restrict__ qb8, const u8* __restrict__ cb8,
    const float* __restrict__ qn, const float* __restrict__ cn,
    const int* __restrict__ rci, const int* __restrict__ filt,
    const float* __restrict__ redq, const float* __restrict__ redc,
    const float* __restrict__ h, const float* __restrict__ emb,
    const float* __restrict__ op, const float* __restrict__ Wp,
    const float* __restrict__ bp, const u16* __restrict__ WxhT,
    const float* __restrict__ bxh, float* __restrict__ prob_out,
    float* __restrict__ outh)
{
  __shared__ char SM[67584];
  u8*    QsF  = (u8*)SM;                  // [32][1024] fp8, chunk-swizzled
  u16*   XH   = (u16*)SM;                 // phase2+: [32 rows] stride 640 B
  float* DOTS = (float*)(SM + 20480);     // [32][8]
  int*   SIDX = (int*)(SM + 32768);       // [256]
  int*   SFLT = (int*)(SM + 33792);       // [256]
  u8*    CsB  = (u8*)(SM + 34816);        // [2][256][64] fp8
  u16*   Bs   = (u16*)(SM + 34816);       // [256][64] bf16 (GRU phase)
  const int tid = threadIdx.x;
  const int lane = tid & 63;
  const int w = tid >> 6;
  const int m0 = blockIdx.x << 5;

  // ---- prologue: q-tile staged ONCE (source chunk-swizzled, rule #21) ----
  #pragma unroll
  for (int i = 0; i < 4; ++i){
    int e = i * 512 + tid;               // 16B chunk id, [0,2048)
    int row = e >> 6, c16 = e & 63;
    gload16(qb8 + (size_t)(m0 + row) * TDIM_ + ((c16 ^ (row & 7)) << 4),
            QsF + e * 16);
  }
  if (tid < 256) SIDX[tid] = rci[m0 * MAXC_ + tid];
  else           SFLT[tid - 256] = filt[m0 * MAXC_ + (tid - 256)];
  __syncthreads();                       // SIDX visible (also drains q-stage)

  auto stageC = [&](int buf, int kt){
    #pragma unroll
    for (int i = 0; i < 2; ++i){
      int e = i * 512 + tid;             // [0,1024)
      int slot = e >> 2, q4 = e & 3;
      int sw = (slot ^ (slot >> 2)) & 3;
      gload16(cb8 + (size_t)SIDX[slot] * TDIM_ + kt * 64 + ((q4 ^ sw) << 4),
              CsB + buf * 16384 + e * 16);
    }
  };

  // ---------- phase 1: dots[32 rows][256 slots] via fp8 MFMA, dbuf ----------
  const int R = w >> 2;
  const int cc0 = (w & 3) * 2;
  f32x4 dacc[2] = {};
  stageC(0, 0);
  int bufc = 0;
  for (int kt = 0; kt < 16; ++kt){
    if (kt < 15){ stageC(bufc ^ 1, kt + 1); VMW(2); }
    else        { VMW(0); }
    BAR();
    const u8* Cs = CsB + bufc * 16384;
    #pragma unroll
    for (int ks = 0; ks < 2; ++ks){
      const int h8 = ks * 4 + (lane >> 4);
      const int arow = R * 16 + (lane & 15);
      const int c16r = kt * 4 + (h8 >> 1);
      i64 a = *(const i64*)(QsF + arow * 1024 + ((c16r ^ (arow & 7)) << 4) + (h8 & 1) * 8);
      #pragma unroll
      for (int t = 0; t < 2; ++t){
        int slot = (R * 8 + cc0 + t) * 16 + (lane & 15);
        int bsw = (slot ^ (slot >> 2)) & 3;
        i64 bfr = *(const i64*)(Cs + slot * 64 + (((h8 >> 1) ^ bsw) << 4) + (h8 & 1) * 8);
        dacc[t] = __builtin_amdgcn_mfma_f32_16x16x32_fp8_fp8(a, bfr, dacc[t], 0, 0, 0);
      }
    }
    BAR();
    bufc ^= 1;
  }
  // extract block-diagonal dots -> DOTS[row][m] (QsF region dead now)
  #pragma unroll
  for (int t = 0; t < 2; ++t){
    const int cc = cc0 + t;
    const int col = lane & 15;
    #pragma unroll
    for (int j = 0; j < 4; ++j){
      int tr = (lane >> 4) * 4 + j;
      if (tr == 2 * cc && col < 8)       DOTS[(R * 16 + tr) * 8 + col] = dacc[t][j];
      if (tr == 2 * cc + 1 && col >= 8)  DOTS[(R * 16 + tr) * 8 + col - 8] = dacc[t][j];
    }
  }
  auto stageB = [&](int kt){
    #pragma unroll
    for (int i = 0; i < 4; ++i){
      int cc = i * 512 + tid;
      int r2 = cc >> 3, s2 = cc & 7;
      gload16(WxhT + (size_t)r2 * 320 + kt * 64 + ((s2 ^ (r2 & 7)) << 3), &Bs[cc * 8]);
    }
  };
  __syncthreads();
  stageB(0);

  // ---------- phase 2: softmax / rep / predictor / xh ----------
  for (int i = 0; i < 4; ++i){
    const int r = w * 4 + i;
    const int b = m0 + r;
    int idxm[MAXC_];
    #pragma unroll
    for (int m = 0; m < MAXC_; ++m) idxm[m] = SIDX[r * MAXC_ + m];
    const float qnb = qn[b];
    float sv[MAXC_]; float mx = -3.0e38f;
    #pragma unroll
    for (int m = 0; m < MAXC_; ++m){
      float dnm = fmaxf(qnb * cn[idxm[m]], 1e-8f);
      float s = (SFLT[r * MAXC_ + m] == 0) ? -1e9f
              : DOTS[r * 8 + m] * (1.f / 1024.f) / dnm;
      sv[m] = s; mx = fmaxf(mx, s);
    }
    float se = 0.f;
    #pragma unroll
    for (int m = 0; m < MAXC_; ++m){ sv[m] = __expf(sv[m] - mx); se += sv[m]; }
    const float inv = 1.f / se;
    float rep = 0.f;
    #pragma unroll
    for (int m = 0; m < MAXC_; ++m) rep += sv[m] * redc[(size_t)idxm[m] * D_ + lane];
    rep *= inv;
    const float v0 = redq[(size_t)b * D_ + lane];
    const float hv = h[(size_t)b * D_ + lane];
    const float e0 = emb[(size_t)b * 128 + lane];
    const float e1 = emb[(size_t)b * 128 + 64 + lane];
    float p = hv * Wp[lane] + v0 * Wp[64 + lane] + rep * Wp[128 + lane]
            + e0 * Wp[192 + lane] + e1 * Wp[256 + lane];
    p = wsum(p);
    if (lane == 0) prob_out[b] = p + bp[0];
    const float o = op[b], om = 1.f - o;
    auto xst = [&](int col, float v){
      *(u16*)((char*)XH + r * 640 + ((col * 2) ^ ((r & 7) << 4))) = f2b(v);
    };
    xst(lane,        v0 * o  + e0 * om);
    xst(64 + lane,   rep * o + e1 * om);
    xst(128 + lane,  v0 * om + e0 * o);
    xst(192 + lane,  rep * om + e1 * o);
    xst(256 + lane,  hv);
  }
  __syncthreads();

  // ---------- phase 3: GRU GEMM [32,320]@[320,256] ----------
  const int lr = lane & 15, lq = lane >> 4;
  const int rh = w & 1, cc2 = w >> 1;
  f32x4 acc[4] = {};
  for (int kt = 0; kt < 5; ++kt){
    VMW(0);
    BAR();
    #pragma unroll
    for (int ks = 0; ks < 2; ++ks){
      const int kb = ks * 64 + lq * 16;
      int rra = rh * 16 + lr;
      bf16x8 af = *(const bf16x8*)((const char*)XH + rra * 640 +
                                   ((kt * 128 + kb) ^ ((rra & 7) << 4)));
      bf16x8 bfr[4];
      #pragma unroll
      for (int fc = 0; fc < 4; ++fc){
        int rr = cc2 * 64 + fc * 16 + lr;
        bfr[fc] = *(const bf16x8*)((const char*)Bs + rr * 128 + (kb ^ ((rr & 7) << 4)));
      }
      #pragma unroll
      for (int fc = 0; fc < 4; ++fc)
        acc[fc] = __builtin_amdgcn_mfma_f32_16x16x32_bf16(af, bfr[fc], acc[fc], 0, 0, 0);
    }
    BAR();
    if (kt < 4) stageB(kt + 1);
  }
  const int d = cc2 * 16 + lr;
  float bg[4];
  #pragma unroll
  for (int g = 0; g < 4; ++g) bg[g] = bxh[cc2 * 64 + g * 16 + lr];
  #pragma unroll
  for (int j = 0; j < 4; ++j){
    float rv = sigf(acc[0][j] + bg[0]);
    float zv = sigf(acc[1][j] + bg[1]);
    float nv = tanhf(acc[2][j] + bg[2] + rv * (acc[3][j] + bg[3]));
    int rr = m0 + rh * 16 + lq * 4 + j;
    float hv = h[(size_t)rr * 64 + d];
    outh[(size_t)rr * 64 + d] = (1.f - zv) * nv + zv * hv;
  }
}

extern "C" void kernel_launch(void* const* d_in, const int* in_sizes, int n_in,
                              void* d_out, int out_size, void* d_ws, size_t ws_size,
                              hipStream_t stream) {
  const int*   prob_ids = (const int*)  d_in[0];
  const int*   rci      = (const int*)  d_in[1];
  const int*   filt     = (const int*)  d_in[2];
  const float* h        = (const float*)d_in[3];
  const float* emb      = (const float*)d_in[4];
  const float* op       = (const float*)d_in[5];
  const float* ex       = (const float*)d_in[6];
  const float* con      = (const float*)d_in[7];
  const float* W1       = (const float*)d_in[8];
  const float* b1       = (const float*)d_in[9];
  const float* W2       = (const float*)d_in[10];
  const float* b2       = (const float*)d_in[11];
  const float* Wp       = (const float*)d_in[12];
  const float* bp       = (const float*)d_in[13];
  const float* Wx       = (const float*)d_in[14];
  const float* Wh       = (const float*)d_in[15];
  const float* bx       = (const float*)d_in[16];
  const float* bh       = (const float*)d_in[17];
  float* out = (float*)d_out;

  char* w = (char*)d_ws;
  size_t off = 0;
  auto alloc = [&](size_t bytes){ size_t o = off; off = (off + bytes + 255) & ~(size_t)255; return o; };
  u8*    qb8  = (u8*)   (w + alloc((size_t)B_ * TDIM_));          // 16 MB
  u8*    cb8  = (u8*)   (w + alloc((size_t)NCONP_ * TDIM_));      // 2 MB
  float* qn   = (float*)(w + alloc((size_t)B_ * 4));
  float* cn   = (float*)(w + alloc((size_t)NCONP_ * 4));
  float* redq = (float*)(w + alloc((size_t)B_ * D_ * 4));         // 4 MB
  float* redc = (float*)(w + alloc((size_t)NCONP_ * D_ * 4));
  u16*   W1T  = (u16*)  (w + alloc((size_t)HID_ * TDIM_ * 2));
  u16*   W2T  = (u16*)  (w + alloc((size_t)D_ * HID_ * 2));
  u16*   WxhT = (u16*)  (w + alloc((size_t)256 * 320 * 2));
  float* bxh  = (float*)(w + alloc((size_t)256 * 4));

  k_prep<<<6017, 256, 0, stream>>>(ex, prob_ids, con, W1, W2, Wx, Wh, bx, bh,
                                   qb8, qn, cb8, cn, W1T, W2T, WxhT, bxh);
  k_mlp<<<576, 512, 0, stream>>>(qb8, cb8, W1T, b1, W2T, b2, redq, redc);
  k_mixgru<<<512, 512, 0, stream>>>(qb8, cb8, qn, cn, rci, filt, redq, redc,
                                    h, emb, op, Wp, bp, WxhT, bxh, out, out + B_);
}

// Round 19
// 70.983 us; speedup vs baseline: 1.3911x; 1.1008x over previous
//
#include <hip/hip_runtime.h>
#include <cstdint>
#include <cstddef>

typedef unsigned short u16;
typedef unsigned char u8;
typedef long long i64;
typedef unsigned long long u64;
typedef __bf16 bf16x8 __attribute__((ext_vector_type(8)));
typedef float f32x4 __attribute__((ext_vector_type(4)));
typedef float f32x2 __attribute__((ext_vector_type(2)));
typedef u16 u16x4 __attribute__((ext_vector_type(4)));
typedef u16 u16x8 __attribute__((ext_vector_type(8)));

#define B_ 16384
#define D_ 64
#define MAXC_ 8
#define NCON_ 2000
#define NCONP_ 2048
#define TDIM_ 1024
#define HID_ 256

#define VMW(n) asm volatile("s_waitcnt vmcnt(" #n ")" ::: "memory")
#define BAR() __builtin_amdgcn_s_barrier()

__device__ inline u16 f2b(float f){
  unsigned u = __float_as_uint(f);
  u += 0x7fffu + ((u >> 16) & 1u);
  return (u16)(u >> 16);
}
__device__ inline float b2f(u16 u){ return __uint_as_float(((unsigned)u) << 16); }

__device__ inline unsigned pk2fp8(float a, float b){
  return (unsigned)__builtin_amdgcn_cvt_pk_fp8_f32(a, b, 0, false);
}

__device__ inline void gload16(const void* g, void* l){
  __builtin_amdgcn_global_load_lds((const __attribute__((address_space(1))) unsigned*)g,
                                   (__attribute__((address_space(3))) unsigned*)l, 16, 0, 0);
}

__device__ inline float wsum(float v){
  #pragma unroll
  for (int o = 32; o; o >>= 1) v += __shfl_xor(v, o);
  return v;
}
__device__ inline float sigf(float x){ return 1.f / (1.f + __expf(-x)); }

// =================== k_prep: fp8 q/c + fp8 W1T + bf16 W2T/WxhT ==============
// [0,4096): q gather ; [4096,4608): concepts ; [4608,5505): weights
__global__ __launch_bounds__(256) void k_prep(
    const float* __restrict__ ex, const int* __restrict__ pid,
    const float* __restrict__ con,
    const float* __restrict__ W1, const float* __restrict__ W2,
    const float* __restrict__ Wx, const float* __restrict__ Wh,
    const float* __restrict__ bx, const float* __restrict__ bh,
    u8* __restrict__ qb8, float* __restrict__ qn,
    u8* __restrict__ cb8, float* __restrict__ cn,
    u8* __restrict__ W1T8, u16* __restrict__ W2T, u16* __restrict__ WxhT,
    float* __restrict__ bxh)
{
  const int bid = blockIdx.x, tid = threadIdx.x;
  const int lane = tid & 63;
  if (bid < 4096){                                  // ---- q gather ----
    const int b = bid * 4 + (tid >> 6);
    const float* src = ex + (size_t)pid[b] * TDIM_;
    u8* dst8 = qb8 + (size_t)b * TDIM_;
    float ss = 0.f;
    #pragma unroll
    for (int c = 0; c < 4; ++c){
      float4 v = *(const float4*)(src + c * 256 + lane * 4);
      ss += v.x*v.x + v.y*v.y + v.z*v.z + v.w*v.w;
      unsigned lo = pk2fp8(v.x * 32.f, v.y * 32.f);
      unsigned hi = pk2fp8(v.z * 32.f, v.w * 32.f);
      *(unsigned*)(dst8 + c * 256 + lane * 4) = (lo & 0xffffu) | (hi << 16);
    }
    ss = wsum(ss);
    if (lane == 0) qn[b] = sqrtf(ss);
  } else if (bid < 4608){                           // ---- concepts ----
    const int r = (bid - 4096) * 4 + (tid >> 6);
    u8* dst8 = cb8 + (size_t)r * TDIM_;
    if (r < NCON_){
      const float* src = con + (size_t)r * TDIM_;
      float ss = 0.f;
      #pragma unroll
      for (int c = 0; c < 4; ++c){
        float4 v = *(const float4*)(src + c * 256 + lane * 4);
        ss += v.x*v.x + v.y*v.y + v.z*v.z + v.w*v.w;
        unsigned lo = pk2fp8(v.x * 32.f, v.y * 32.f);
        unsigned hi = pk2fp8(v.z * 32.f, v.w * 32.f);
        *(unsigned*)(dst8 + c * 256 + lane * 4) = (lo & 0xffffu) | (hi << 16);
      }
      ss = wsum(ss);
      if (lane == 0) cn[r] = sqrtf(ss);
    } else {
      #pragma unroll
      for (int c = 0; c < 4; ++c)
        *(unsigned*)(dst8 + c * 256 + lane * 4) = 0u;
    }
  } else {                                          // ---- weights ----
    int gid = (bid - 4608) * 256 + tid;
    if (gid < 131072){                       // W1T8: n*1024 + k (pairs)
      int n = gid >> 9, k2 = (gid & 511) * 2;
      unsigned pk = pk2fp8(W1[(size_t)k2 * 256 + n] * 32.f,
                           W1[(size_t)(k2 + 1) * 256 + n] * 32.f);
      *(u16*)(W1T8 + (size_t)n * 1024 + k2) = (u16)pk;
    } else if (gid < 147456){                // W2T: n*256 + k
      int t = gid - 131072;
      int n = t >> 8, k = t & 255;
      W2T[t] = f2b(W2[(size_t)k * 64 + n]);
    } else if (gid < 229376){                // WxhT: c*320 + k, gate-interleaved
      int t = gid - 147456;
      int c = t / 320, k = t % 320;
      int g = (c >> 4) & 3;
      int d = (c >> 6) * 16 + (c & 15);
      float v = 0.f;
      if (k < 256){
        if (g == 0)      v = Wx[(size_t)k * 192 + d];
        else if (g == 1) v = Wx[(size_t)k * 192 + 64 + d];
        else if (g == 2) v = Wx[(size_t)k * 192 + 128 + d];
      } else {
        int kh = k - 256;
        if (g == 0)      v = Wh[(size_t)kh * 192 + d];
        else if (g == 1) v = Wh[(size_t)kh * 192 + 64 + d];
        else if (g == 3) v = Wh[(size_t)kh * 192 + 128 + d];
      }
      WxhT[t] = f2b(v);
    } else if (gid < 229632){                // bxh
      int c = gid - 229376;
      int g = (c >> 4) & 3;
      int d = (c >> 6) * 16 + (c & 15);
      float v;
      if (g == 0)      v = bx[d] + bh[d];
      else if (g == 1) v = bx[64 + d] + bh[64 + d];
      else if (g == 2) v = bx[128 + d];
      else             v = bh[128 + d];
      bxh[c] = v;
    }
  }
}

// =================== k_mlp: fp8 layer-1 GEMM (dbuf, counted vmcnt) ==========
// BM=32, 576 blocks x 512 thr. A(fp8)@W1T8(fp8) via mfma_fp8; layer 2 bf16.
// LDS: AB[2] (2KB A + 16KB B each) + Hs 16 KB = 52 KB -> 3 blocks/CU.
__global__ __launch_bounds__(512) void k_mlp(
    const u8* __restrict__ qb8, const u8* __restrict__ cb8,
    const u8* __restrict__ W1T8, const float* __restrict__ b1,
    const u16* __restrict__ W2T, const float* __restrict__ b2,
    float* __restrict__ redq, float* __restrict__ redc)
{
  __shared__ char SMm[53248];
  // buf b: A at b*18432, B at b*18432+2048 ; Hs at 36864
  u16* Hs = (u16*)(SMm + 36864);
  const int tid = threadIdx.x;
  const int lane = tid & 63;
  const int w = tid >> 6;
  const int lr = lane & 15, lq = lane >> 4;
  const bool qside = blockIdx.x < 512;
  const u8* Abase = qside ? qb8 : cb8;
  float* Obase = qside ? redq : redc;
  const int m0 = (qside ? (int)blockIdx.x : ((int)blockIdx.x - 512)) << 5;
  const int rf = w & 1, ch = w >> 1;

  auto stage = [&](int buf, int kt){
    u8* Ab = (u8*)SMm + buf * 18432;
    u8* Bb = Ab + 2048;
    #pragma unroll
    for (int i = 0; i < 2; ++i){
      int e = i * 512 + tid;               // [0,1024) B chunks
      int slot = e >> 2, q4 = e & 3;
      int sw = (slot ^ (slot >> 2)) & 3;
      gload16(W1T8 + (size_t)slot * 1024 + kt * 64 + ((q4 ^ sw) << 4), Bb + e * 16);
    }
    if (tid < 128){                        // A chunks
      int slot = tid >> 2, q4 = tid & 3;
      int sw = (slot ^ (slot >> 2)) & 3;
      gload16(Abase + (size_t)(m0 + slot) * TDIM_ + kt * 64 + ((q4 ^ sw) << 4),
              Ab + tid * 16);
    }
  };

  f32x4 acc[4] = {};
  stage(0, 0);
  int buf = 0;
  for (int kt = 0; kt < 16; ++kt){
    if (kt < 15){
      stage(buf ^ 1, kt + 1);
      if (w < 2) VMW(3); else VMW(2);
    } else VMW(0);
    BAR();
    const u8* Ab = (const u8*)SMm + buf * 18432;
    const u8* Bb = Ab + 2048;
    #pragma unroll
    for (int ks = 0; ks < 2; ++ks){
      const int h8 = ks * 4 + lq;
      const int arow = rf * 16 + lr;
      const int asw = (arow ^ (arow >> 2)) & 3;
      i64 a = *(const i64*)(Ab + arow * 64 + (((h8 >> 1) ^ asw) << 4) + (h8 & 1) * 8);
      #pragma unroll
      for (int fc = 0; fc < 4; ++fc){
        int brow = ch * 64 + fc * 16 + lr;
        int bsw = (brow ^ (brow >> 2)) & 3;
        i64 bv = *(const i64*)(Bb + brow * 64 + (((h8 >> 1) ^ bsw) << 4) + (h8 & 1) * 8);
        acc[fc] = __builtin_amdgcn_mfma_f32_16x16x32_fp8_fp8(a, bv, acc[fc], 0, 0, 0);
      }
    }
    BAR();
    buf ^= 1;
  }
  #pragma unroll
  for (int fc = 0; fc < 4; ++fc){
    int col = ch * 64 + fc * 16 + lr;
    float bv = b1[col];
    #pragma unroll
    for (int j = 0; j < 4; ++j){
      int rr = rf * 16 + lq * 4 + j;
      float v = fmaxf(acc[fc][j] * (1.f / 1024.f) + bv, 0.f);
      *(u16*)((char*)Hs + rr * 512 + ((col * 2) ^ ((rr & 7) << 4))) = f2b(v);
    }
  }
  __syncthreads();
  const int rf2 = w & 1, cp = w >> 1;
  f32x4 acc2 = {};
  #pragma unroll
  for (int ks2 = 0; ks2 < 8; ++ks2){
    int rr = rf2 * 16 + lr;
    int kb2 = ks2 * 64 + lq * 16;
    bf16x8 af2 = *(const bf16x8*)((const char*)Hs + rr * 512 + (kb2 ^ ((rr & 7) << 4)));
    bf16x8 w2 = *(const bf16x8*)(W2T + (size_t)(cp * 16 + lr) * 256 + ks2 * 32 + lq * 8);
    acc2 = __builtin_amdgcn_mfma_f32_16x16x32_bf16(af2, w2, acc2, 0, 0, 0);
  }
  {
    int col = cp * 16 + lr;
    float bv = b2[col];
    #pragma unroll
    for (int j = 0; j < 4; ++j){
      int rr = m0 + rf2 * 16 + lq * 4 + j;
      Obase[(size_t)rr * 64 + col] = acc2[j] + bv;
    }
  }
}

// =================== k_mixgru (exact R18): dbuf MFMA dots + mix + GRU =======
__global__ __launch_bounds__(512) void k_mixgru(
    const u8* __restrict__ qb8, const u8* __restrict__ cb8,
    const float* __restrict__ qn, const float* __restrict__ cn,
    const int* __restrict__ rci, const int* __restrict__ filt,
    const float* __restrict__ redq, const float* __restrict__ redc,
    const float* __restrict__ h, const float* __restrict__ emb,
    const float* __restrict__ op, const float* __restrict__ Wp,
    const float* __restrict__ bp, const u16* __restrict__ WxhT,
    const float* __restrict__ bxh, float* __restrict__ prob_out,
    float* __restrict__ outh)
{
  __shared__ char SM[67584];
  u8*    QsF  = (u8*)SM;                  // [32][1024] fp8, chunk-swizzled
  u16*   XH   = (u16*)SM;                 // phase2+: [32 rows] stride 640 B
  float* DOTS = (float*)(SM + 20480);     // [32][8]
  int*   SIDX = (int*)(SM + 32768);       // [256]
  int*   SFLT = (int*)(SM + 33792);       // [256]
  u8*    CsB  = (u8*)(SM + 34816);        // [2][256][64] fp8
  u16*   Bs   = (u16*)(SM + 34816);       // [256][64] bf16 (GRU phase)
  const int tid = threadIdx.x;
  const int lane = tid & 63;
  const int w = tid >> 6;
  const int m0 = blockIdx.x << 5;

  #pragma unroll
  for (int i = 0; i < 4; ++i){
    int e = i * 512 + tid;
    int row = e >> 6, c16 = e & 63;
    gload16(qb8 + (size_t)(m0 + row) * TDIM_ + ((c16 ^ (row & 7)) << 4),
            QsF + e * 16);
  }
  if (tid < 256) SIDX[tid] = rci[m0 * MAXC_ + tid];
  else           SFLT[tid - 256] = filt[m0 * MAXC_ + (tid - 256)];
  __syncthreads();

  auto stageC = [&](int buf, int kt){
    #pragma unroll
    for (int i = 0; i < 2; ++i){
      int e = i * 512 + tid;
      int slot = e >> 2, q4 = e & 3;
      int sw = (slot ^ (slot >> 2)) & 3;
      gload16(cb8 + (size_t)SIDX[slot] * TDIM_ + kt * 64 + ((q4 ^ sw) << 4),
              CsB + buf * 16384 + e * 16);
    }
  };

  const int R = w >> 2;
  const int cc0 = (w & 3) * 2;
  f32x4 dacc[2] = {};
  stageC(0, 0);
  int bufc = 0;
  for (int kt = 0; kt < 16; ++kt){
    if (kt < 15){ stageC(bufc ^ 1, kt + 1); VMW(2); }
    else        { VMW(0); }
    BAR();
    const u8* Cs = CsB + bufc * 16384;
    #pragma unroll
    for (int ks = 0; ks < 2; ++ks){
      const int h8 = ks * 4 + (lane >> 4);
      const int arow = R * 16 + (lane & 15);
      const int c16r = kt * 4 + (h8 >> 1);
      i64 a = *(const i64*)(QsF + arow * 1024 + ((c16r ^ (arow & 7)) << 4) + (h8 & 1) * 8);
      #pragma unroll
      for (int t = 0; t < 2; ++t){
        int slot = (R * 8 + cc0 + t) * 16 + (lane & 15);
        int bsw = (slot ^ (slot >> 2)) & 3;
        i64 bfr = *(const i64*)(Cs + slot * 64 + (((h8 >> 1) ^ bsw) << 4) + (h8 & 1) * 8);
        dacc[t] = __builtin_amdgcn_mfma_f32_16x16x32_fp8_fp8(a, bfr, dacc[t], 0, 0, 0);
      }
    }
    BAR();
    bufc ^= 1;
  }
  #pragma unroll
  for (int t = 0; t < 2; ++t){
    const int cc = cc0 + t;
    const int col = lane & 15;
    #pragma unroll
    for (int j = 0; j < 4; ++j){
      int tr = (lane >> 4) * 4 + j;
      if (tr == 2 * cc && col < 8)       DOTS[(R * 16 + tr) * 8 + col] = dacc[t][j];
      if (tr == 2 * cc + 1 && col >= 8)  DOTS[(R * 16 + tr) * 8 + col - 8] = dacc[t][j];
    }
  }
  auto stageB = [&](int kt){
    #pragma unroll
    for (int i = 0; i < 4; ++i){
      int cc = i * 512 + tid;
      int r2 = cc >> 3, s2 = cc & 7;
      gload16(WxhT + (size_t)r2 * 320 + kt * 64 + ((s2 ^ (r2 & 7)) << 3), &Bs[cc * 8]);
    }
  };
  __syncthreads();
  stageB(0);

  for (int i = 0; i < 4; ++i){
    const int r = w * 4 + i;
    const int b = m0 + r;
    int idxm[MAXC_];
    #pragma unroll
    for (int m = 0; m < MAXC_; ++m) idxm[m] = SIDX[r * MAXC_ + m];
    const float qnb = qn[b];
    float sv[MAXC_]; float mx = -3.0e38f;
    #pragma unroll
    for (int m = 0; m < MAXC_; ++m){
      float dnm = fmaxf(qnb * cn[idxm[m]], 1e-8f);
      float s = (SFLT[r * MAXC_ + m] == 0) ? -1e9f
              : DOTS[r * 8 + m] * (1.f / 1024.f) / dnm;
      sv[m] = s; mx = fmaxf(mx, s);
    }
    float se = 0.f;
    #pragma unroll
    for (int m = 0; m < MAXC_; ++m){ sv[m] = __expf(sv[m] - mx); se += sv[m]; }
    const float inv = 1.f / se;
    float rep = 0.f;
    #pragma unroll
    for (int m = 0; m < MAXC_; ++m) rep += sv[m] * redc[(size_t)idxm[m] * D_ + lane];
    rep *= inv;
    const float v0 = redq[(size_t)b * D_ + lane];
    const float hv = h[(size_t)b * D_ + lane];
    const float e0 = emb[(size_t)b * 128 + lane];
    const float e1 = emb[(size_t)b * 128 + 64 + lane];
    float p = hv * Wp[lane] + v0 * Wp[64 + lane] + rep * Wp[128 + lane]
            + e0 * Wp[192 + lane] + e1 * Wp[256 + lane];
    p = wsum(p);
    if (lane == 0) prob_out[b] = p + bp[0];
    const float o = op[b], om = 1.f - o;
    auto xst = [&](int col, float v){
      *(u16*)((char*)XH + r * 640 + ((col * 2) ^ ((r & 7) << 4))) = f2b(v);
    };
    xst(lane,        v0 * o  + e0 * om);
    xst(64 + lane,   rep * o + e1 * om);
    xst(128 + lane,  v0 * om + e0 * o);
    xst(192 + lane,  rep * om + e1 * o);
    xst(256 + lane,  hv);
  }
  __syncthreads();

  const int lr = lane & 15, lq = lane >> 4;
  const int rh = w & 1, cc2 = w >> 1;
  f32x4 acc[4] = {};
  for (int kt = 0; kt < 5; ++kt){
    VMW(0);
    BAR();
    #pragma unroll
    for (int ks = 0; ks < 2; ++ks){
      const int kb = ks * 64 + lq * 16;
      int rra = rh * 16 + lr;
      bf16x8 af = *(const bf16x8*)((const char*)XH + rra * 640 +
                                   ((kt * 128 + kb) ^ ((rra & 7) << 4)));
      bf16x8 bfr[4];
      #pragma unroll
      for (int fc = 0; fc < 4; ++fc){
        int rr = cc2 * 64 + fc * 16 + lr;
        bfr[fc] = *(const bf16x8*)((const char*)Bs + rr * 128 + (kb ^ ((rr & 7) << 4)));
      }
      #pragma unroll
      for (int fc = 0; fc < 4; ++fc)
        acc[fc] = __builtin_amdgcn_mfma_f32_16x16x32_bf16(af, bfr[fc], acc[fc], 0, 0, 0);
    }
    BAR();
    if (kt < 4) stageB(kt + 1);
  }
  const int d = cc2 * 16 + lr;
  float bg[4];
  #pragma unroll
  for (int g = 0; g < 4; ++g) bg[g] = bxh[cc2 * 64 + g * 16 + lr];
  #pragma unroll
  for (int j = 0; j < 4; ++j){
    float rv = sigf(acc[0][j] + bg[0]);
    float zv = sigf(acc[1][j] + bg[1]);
    float nv = tanhf(acc[2][j] + bg[2] + rv * (acc[3][j] + bg[3]));
    int rr = m0 + rh * 16 + lq * 4 + j;
    float hv = h[(size_t)rr * 64 + d];
    outh[(size_t)rr * 64 + d] = (1.f - zv) * nv + zv * hv;
  }
}

extern "C" void kernel_launch(void* const* d_in, const int* in_sizes, int n_in,
                              void* d_out, int out_size, void* d_ws, size_t ws_size,
                              hipStream_t stream) {
  const int*   prob_ids = (const int*)  d_in[0];
  const int*   rci      = (const int*)  d_in[1];
  const int*   filt     = (const int*)  d_in[2];
  const float* h        = (const float*)d_in[3];
  const float* emb      = (const float*)d_in[4];
  const float* op       = (const float*)d_in[5];
  const float* ex       = (const float*)d_in[6];
  const float* con      = (const float*)d_in[7];
  const float* W1       = (const float*)d_in[8];
  const float* b1       = (const float*)d_in[9];
  const float* W2       = (const float*)d_in[10];
  const float* b2       = (const float*)d_in[11];
  const float* Wp       = (const float*)d_in[12];
  const float* bp       = (const float*)d_in[13];
  const float* Wx       = (const float*)d_in[14];
  const float* Wh       = (const float*)d_in[15];
  const float* bx       = (const float*)d_in[16];
  const float* bh       = (const float*)d_in[17];
  float* out = (float*)d_out;

  char* w = (char*)d_ws;
  size_t off = 0;
  auto alloc = [&](size_t bytes){ size_t o = off; off = (off + bytes + 255) & ~(size_t)255; return o; };
  u8*    qb8  = (u8*)   (w + alloc((size_t)B_ * TDIM_));          // 16 MB
  u8*    cb8  = (u8*)   (w + alloc((size_t)NCONP_ * TDIM_));      // 2 MB
  float* qn   = (float*)(w + alloc((size_t)B_ * 4));
  float* cn   = (float*)(w + alloc((size_t)NCONP_ * 4));
  float* redq = (float*)(w + alloc((size_t)B_ * D_ * 4));         // 4 MB
  float* redc = (float*)(w + alloc((size_t)NCONP_ * D_ * 4));
  u8*    W1T8 = (u8*)   (w + alloc((size_t)HID_ * TDIM_));        // 256 KB
  u16*   W2T  = (u16*)  (w + alloc((size_t)D_ * HID_ * 2));
  u16*   WxhT = (u16*)  (w + alloc((size_t)256 * 320 * 2));
  float* bxh  = (float*)(w + alloc((size_t)256 * 4));

  k_prep<<<5505, 256, 0, stream>>>(ex, prob_ids, con, W1, W2, Wx, Wh, bx, bh,
                                   qb8, qn, cb8, cn, W1T8, W2T, WxhT, bxh);
  k_mlp<<<576, 512, 0, stream>>>(qb8, cb8, W1T8, b1, W2T, b2, redq, redc);
  k_mixgru<<<512, 512, 0, stream>>>(qb8, cb8, qn, cn, rci, filt, redq, redc,
                                    h, emb, op, Wp, bp, WxhT, bxh, out, out + B_);
}